// Round 3
// baseline (348.534 us; speedup 1.0000x reference)
//
#include <hip/hip_runtime.h>

typedef unsigned short u16;
typedef float  f32x4 __attribute__((ext_vector_type(4)));
typedef short  s16x8 __attribute__((ext_vector_type(8)));

#define DEV static __device__ __forceinline__

DEV u16 f2bf(float f){ union{float f; unsigned int i;} c; c.f=f; unsigned int i=c.i;
                       return (u16)((i + 0x7FFFu + ((i>>16)&1u))>>16); }

// 16x16x32 A/B fragment load: 4 contiguous bf16 at p, 4 at p+16.
// Same assumed k-map mu(lq,e) for ALL operands (incl. D->B repack) -> permutation-safe.
DEV s16x8 ld_frag(const u16* p){
  union{ s16x8 v; uint2 u[2]; } r;
  r.u[0] = *(const uint2*)(p);
  r.u[1] = *(const uint2*)(p+16);
  return r.v;
}

// Repack 16 bf16 values from D-chunks (chunk f holds k = f*16 + lq*4 + r)
// into 2 B-operand frags over a 64-wide k dim, matching mu(lq,e).
DEV void repack64(const u16 pb[16], s16x8 pf[2]){
  #pragma unroll
  for(int kc=0;kc<2;kc++){
    union{s16x8 v; u16 e[8];} u;
    #pragma unroll
    for(int e=0;e<4;e++){ u.e[e]=pb[(2*kc)*4+e]; u.e[4+e]=pb[(2*kc+1)*4+e]; }
    pf[kc]=u.v;
  }
}

// ---------------- Kernel 0: fp32 -> bf16 conversion ----------------
__global__ __launch_bounds__(256) void cvt_kernel(const float* __restrict__ src,
                                                  u16* __restrict__ dst, int n4)
{
  int i = blockIdx.x*256 + threadIdx.x;
  if (i >= n4) return;
  float4 v = *(const float4*)(src + (size_t)i*4);
  ushort4 o;
  o.x = f2bf(v.x); o.y = f2bf(v.y); o.z = f2bf(v.z); o.w = f2bf(v.w);
  *(ushort4*)(dst + (size_t)i*4) = o;
}

// ---------------- Kernel 1: K/V projection for a 4-batch half ----------------
// out[bl*8+h][n][kk] = sum_c x[bl][n][c] * W[h][kk][c];  M = 4*2048 = 8192 rows
__global__ __launch_bounds__(256) void kv_kernel(
    const u16* __restrict__ x, const u16* __restrict__ Wk,
    const u16* __restrict__ Wv, u16* __restrict__ kb, u16* __restrict__ vb)
{
  const u16* W = blockIdx.z ? Wv : Wk;
  u16* out = blockIdx.z ? vb : kb;
  const int m0 = blockIdx.x*64, j0 = blockIdx.y*64;
  __shared__ u16 at[64][40];
  __shared__ u16 bt[64][40];
  const int tid = threadIdx.x, lane = tid&63, w = tid>>6;
  const int wm = w>>1, wn = w&1;
  const int l16 = lane&15, lq = lane>>4;
  f32x4 acc[2][2] = {};
  const int srow = tid>>2, scol = (tid&3)*8;
  for (int c0=0;c0<256;c0+=32){
    *(uint4*)&at[srow][scol] = *(const uint4*)&x[(size_t)(m0+srow)*256 + c0 + scol];
    *(uint4*)&bt[srow][scol] = *(const uint4*)&W[(size_t)(j0+srow)*256 + c0 + scol];
    __syncthreads();
    s16x8 af[2], bfr[2];
    #pragma unroll
    for(int mf=0;mf<2;mf++) af[mf]  = ld_frag(&at[wm*32+mf*16+l16][lq*4]);
    #pragma unroll
    for(int nf=0;nf<2;nf++) bfr[nf] = ld_frag(&bt[wn*32+nf*16+l16][lq*4]);
    #pragma unroll
    for(int mf=0;mf<2;mf++)
      #pragma unroll
      for(int nf=0;nf<2;nf++)
        acc[mf][nf] = __builtin_amdgcn_mfma_f32_16x16x32_bf16(af[mf], bfr[nf], acc[mf][nf],0,0,0);
    __syncthreads();
  }
  // D layout: col = lane&15, row = (lane>>4)*4 + r
  #pragma unroll
  for(int mf=0;mf<2;mf++)
    #pragma unroll
    for(int nf=0;nf<2;nf++)
      #pragma unroll
      for(int r=0;r<4;r++){
        int m = m0 + wm*32 + mf*16 + lq*4 + r;
        int j = j0 + wn*32 + nf*16 + l16;
        int bl = m>>11, n = m&2047, h = j>>6, kk = j&63;
        out[(size_t)((bl<<3)|h)*131072 + (size_t)n*64 + kk] = f2bf(acc[mf][nf][r]);
      }
}

// ---------------- Kernel 2: fused Q-projection + flash attention ----------------
__global__ __launch_bounds__(256) void attn_kernel(
    const u16* __restrict__ x, const u16* __restrict__ Wq,
    const u16* __restrict__ kb, const u16* __restrict__ vb,
    u16* __restrict__ cat)
{
  const int bhl = blockIdx.y;           // 0..31 within half
  const int bl = bhl>>3, h = bhl&7;
  const u16* xg = x + (size_t)bl*524288;          // 2048*256
  const u16* kg = kb + (size_t)bhl*131072;
  const u16* vg = vb + (size_t)bhl*131072;
  u16* catp = cat + (size_t)bl*1048576 + h*64;
  const int tid=threadIdx.x, lane=tid&63, w=tid>>6;
  const int l16=lane&15, lq=lane>>4;
  const int n0 = blockIdx.x*64;
  __shared__ u16 kt[64][72];
  __shared__ u16 vt[64][72];

  // ---- Q on the fly: D_q[dk][i] = sum_c Wq[h][dk][c] * x[i][c] ----
  s16x8 qf[2];
  {
    const u16* wqh = Wq + (size_t)h*16384;        // 64*256
    const int row = n0 + w*16 + l16;              // query i owned by this lane
    s16x8 xf[8];
    #pragma unroll
    for(int kc8=0;kc8<8;kc8++) xf[kc8] = ld_frag(xg + (size_t)row*256 + kc8*32 + lq*4);
    f32x4 dq[4] = {};
    #pragma unroll
    for(int df=0;df<4;df++)
      #pragma unroll
      for(int kc8=0;kc8<8;kc8++){
        s16x8 wf = ld_frag(wqh + (size_t)(df*16+l16)*256 + kc8*32 + lq*4);
        dq[df] = __builtin_amdgcn_mfma_f32_16x16x32_bf16(wf, xf[kc8], dq[df],0,0,0);
      }
    u16 qb16[16];
    #pragma unroll
    for(int df=0;df<4;df++)
      #pragma unroll
      for(int r=0;r<4;r++) qb16[df*4+r] = f2bf(dq[df][r]);   // dk = df*16+lq*4+r
    repack64(qb16, qf);
  }

  f32x4 oacc[4]={};
  float mrun = -1e30f, lrun = 0.f;
  const int srow = tid>>2, sc0 = (tid&3)*16;
  for(int t=0;t<32;t++){
    {
      const u16* ks = kg + (size_t)(t*64+srow)*64 + sc0;
      *(uint4*)&kt[srow][sc0]   = *(const uint4*)ks;
      *(uint4*)&kt[srow][sc0+8] = *(const uint4*)(ks+8);
      const u16* vs = vg + (size_t)(t*64+srow)*64 + sc0;
      union{uint4 u4[2]; u16 e[16];} vv;
      vv.u4[0]=*(const uint4*)vs; vv.u4[1]=*(const uint4*)(vs+8);
      #pragma unroll
      for(int e=0;e<16;e++) vt[sc0+e][srow] = vv.e[e];
    }
    __syncthreads();
    f32x4 sacc[4]={};
    #pragma unroll
    for(int jf=0;jf<4;jf++)
      #pragma unroll
      for(int kc=0;kc<2;kc++){
        s16x8 kf = ld_frag(&kt[jf*16+l16][kc*32+lq*4]);
        sacc[jf]=__builtin_amdgcn_mfma_f32_16x16x32_bf16(kf, qf[kc], sacc[jf],0,0,0);
      }
    float s[4][4], mloc=-1e30f;
    #pragma unroll
    for(int jf=0;jf<4;jf++)
      #pragma unroll
      for(int r=0;r<4;r++){
        float val = sacc[jf][r]*0.125f;
        s[jf][r]=val; mloc = fmaxf(mloc,val);
      }
    mloc = fmaxf(mloc, __shfl_xor(mloc,16,64));
    mloc = fmaxf(mloc, __shfl_xor(mloc,32,64));
    const float mnew = fmaxf(mrun, mloc);
    const float alpha = __expf(mrun - mnew);
    float rsum = 0.f;
    u16 pb[16];
    #pragma unroll
    for(int jf=0;jf<4;jf++)
      #pragma unroll
      for(int r=0;r<4;r++){
        float p = __expf(s[jf][r]-mnew);
        rsum += p;
        pb[jf*4+r] = f2bf(p);                     // j = jf*16+lq*4+r
      }
    rsum += __shfl_xor(rsum,16,64);
    rsum += __shfl_xor(rsum,32,64);
    lrun = lrun*alpha + rsum;
    mrun = mnew;
    #pragma unroll
    for(int cf=0;cf<4;cf++)
      #pragma unroll
      for(int r=0;r<4;r++) oacc[cf][r]*=alpha;
    s16x8 pf[2];
    repack64(pb, pf);
    #pragma unroll
    for(int cf=0;cf<4;cf++)
      #pragma unroll
      for(int kc=0;kc<2;kc++){
        s16x8 vf = ld_frag(&vt[cf*16+l16][kc*32+lq*4]);
        oacc[cf]=__builtin_amdgcn_mfma_f32_16x16x32_bf16(vf, pf[kc], oacc[cf],0,0,0);
      }
    __syncthreads();
  }
  const float rinv = 1.f/lrun;
  const int n = n0 + w*16 + l16;
  #pragma unroll
  for(int cf=0;cf<4;cf++)
    #pragma unroll
    for(int r=0;r<4;r++){
      int c = cf*16 + lq*4 + r;
      catp[(size_t)n*512 + c] = f2bf(oacc[cf][r]*rinv);
    }
}

// ---------------- Kernel 3: output projection + BN + LeakyReLU (fp32 out) ----------------
__global__ __launch_bounds__(256) void proj_kernel(
    const u16* __restrict__ cat, const u16* __restrict__ Wp,
    const float* __restrict__ gamma, const float* __restrict__ beta,
    const float* __restrict__ mean,  const float* __restrict__ var,
    float* __restrict__ out)
{
  const int m0 = blockIdx.x*64, j0 = blockIdx.y*64;
  __shared__ u16 at[64][40];
  __shared__ u16 bt[64][40];
  const int tid=threadIdx.x, lane=tid&63, w=tid>>6;
  const int wm=w>>1, wn=w&1, l16=lane&15, lq=lane>>4;
  f32x4 acc[2][2]={};
  const int srow=tid>>2, scol=(tid&3)*8;
  for(int c0=0;c0<512;c0+=32){
    *(uint4*)&at[srow][scol] = *(const uint4*)&cat[(size_t)(m0+srow)*512 + c0+scol];
    *(uint4*)&bt[srow][scol] = *(const uint4*)&Wp[(size_t)(j0+srow)*512 + c0+scol];
    __syncthreads();
    s16x8 af[2],bfr[2];
    #pragma unroll
    for(int mf=0;mf<2;mf++) af[mf]=ld_frag(&at[wm*32+mf*16+l16][lq*4]);
    #pragma unroll
    for(int nf=0;nf<2;nf++) bfr[nf]=ld_frag(&bt[wn*32+nf*16+l16][lq*4]);
    #pragma unroll
    for(int mf=0;mf<2;mf++)
      #pragma unroll
      for(int nf=0;nf<2;nf++)
        acc[mf][nf]=__builtin_amdgcn_mfma_f32_16x16x32_bf16(af[mf],bfr[nf],acc[mf][nf],0,0,0);
    __syncthreads();
  }
  #pragma unroll
  for(int nf=0;nf<2;nf++){
    const int co = j0 + wn*32 + nf*16 + l16;
    const float g=gamma[co], be=beta[co], mu=mean[co], va=var[co];
    const float a  = g * rsqrtf(va + 1e-5f);
    const float b2 = be - mu*a;
    #pragma unroll
    for(int mf=0;mf<2;mf++)
      #pragma unroll
      for(int r=0;r<4;r++){
        int m = m0 + wm*32 + mf*16 + lq*4 + r;
        float y = acc[mf][nf][r]*a + b2;
        y = (y>=0.f)? y : 0.01f*y;
        out[(size_t)m*256 + co] = y;
      }
  }
}

extern "C" void kernel_launch(void* const* d_in, const int* in_sizes, int n_in,
                              void* d_out, int out_size, void* d_ws, size_t ws_size,
                              hipStream_t stream)
{
  const float* x  = (const float*)d_in[0];
  const float* Wq = (const float*)d_in[1];
  const float* Wk = (const float*)d_in[2];
  const float* Wv = (const float*)d_in[3];
  const float* Wp = (const float*)d_in[4];
  const float* g  = (const float*)d_in[5];
  const float* be = (const float*)d_in[6];
  const float* mu = (const float*)d_in[7];
  const float* va = (const float*)d_in[8];

  u16* ws   = (u16*)d_ws;
  u16* x16  = ws;                         // 4,194,304 elems (8 MiB)
  u16* wq16 = ws + 4194304;               // 131072
  u16* wk16 = ws + 4325376;               // 131072
  u16* wv16 = ws + 4456448;               // 131072
  u16* wp16 = ws + 4587520;               // 131072
  u16* kb   = ws + 4718592;               // 32 bh * 131072 = 4,194,304 (8 MiB)
  u16* vb   = ws + 8912896;               // 4,194,304 (8 MiB)
  u16* cat  = ws + 13107200;              // 8,388,608 (16 MiB)  -> total ~41 MiB

  cvt_kernel<<<4096, 256, 0, stream>>>(x,  x16,  1048576);
  cvt_kernel<<<128,  256, 0, stream>>>(Wq, wq16, 32768);
  cvt_kernel<<<128,  256, 0, stream>>>(Wk, wk16, 32768);
  cvt_kernel<<<128,  256, 0, stream>>>(Wv, wv16, 32768);
  cvt_kernel<<<128,  256, 0, stream>>>(Wp, wp16, 32768);

  for (int half = 0; half < 2; ++half){
    const u16* xh = x16 + (size_t)half*2097152;   // 4 batches * 2048 * 256
    u16* cath = cat + (size_t)half*4194304;       // 4 batches * 2048 * 512
    kv_kernel<<<dim3(128,8,2), dim3(256), 0, stream>>>(xh, wk16, wv16, kb, vb);
    attn_kernel<<<dim3(32,32), dim3(256), 0, stream>>>(xh, wq16, kb, vb, cath);
  }
  proj_kernel<<<dim3(256,4), dim3(256), 0, stream>>>(cat, wp16, g, be, mu, va, (float*)d_out);
}

// Round 4
// 233.879 us; speedup vs baseline: 1.4902x; 1.4902x over previous
//
#include <hip/hip_runtime.h>
#include <hip/hip_bf16.h>

typedef unsigned short u16;
typedef unsigned int u32;
typedef float  f32x4 __attribute__((ext_vector_type(4)));
typedef short  s16x8 __attribute__((ext_vector_type(8)));

#define DEV static __device__ __forceinline__

DEV u16 f2bf(float f){ union{float f; unsigned int i;} c; c.f=f; unsigned int i=c.i;
                       return (u16)((i + 0x7FFFu + ((i>>16)&1u))>>16); }

// packed 2x f32 -> bf16x2 (v_cvt_pk_bf16_f32), low word = a
DEV u32 pkbf(float a, float b){
  union{ __hip_bfloat162 h; u32 u; } c;
  c.h = __float22bfloat162_rn(make_float2(a, b));
  return c.u;
}

DEV float exp2a(float x){
#if __has_builtin(__builtin_amdgcn_exp2f)
  return __builtin_amdgcn_exp2f(x);
#else
  return exp2f(x);
#endif
}

// 16x16x32 A/B fragment from plain layout: 4 contiguous bf16 at p, 4 at p+16.
// k-map mu(lq,e): e<4 -> lq*4+e ; e>=4 -> 16+lq*4+(e-4). Used identically for
// all operands -> permutation-safe.
DEV s16x8 ld_frag(const u16* p){
  union{ s16x8 v; uint2 u[2]; } r;
  r.u[0] = *(const uint2*)(p);
  r.u[1] = *(const uint2*)(p+16);
  return r.v;
}

// ---------------- Kernel 0: fp32 -> bf16 ----------------
__global__ __launch_bounds__(256) void cvt_kernel(const float* __restrict__ src,
                                                  u16* __restrict__ dst, int n4)
{
  int i = blockIdx.x*256 + threadIdx.x;
  if (i >= n4) return;
  float4 v = *(const float4*)(src + (size_t)i*4);
  ushort4 o;
  o.x = f2bf(v.x); o.y = f2bf(v.y); o.z = f2bf(v.z); o.w = f2bf(v.w);
  *(ushort4*)(dst + (size_t)i*4) = o;
}

// ---------------- Kernel 1: K/V projection (4-batch half) ----------------
// K stored [bh][n][kk'] with kk' fragment-permuted; V stored transposed
// [bh][dv][n'] with n' fragment-permuted within each 64-tile.
__global__ __launch_bounds__(256) void kv_kernel(
    const u16* __restrict__ x, const u16* __restrict__ Wk,
    const u16* __restrict__ Wv, u16* __restrict__ kbuf, u16* __restrict__ vbuf)
{
  const int isV = blockIdx.z;
  const u16* W = isV ? Wv : Wk;
  const int m0 = blockIdx.x*64, j0 = blockIdx.y*64;
  __shared__ u16 at[64][40];
  __shared__ u16 bt[64][40];
  const int tid = threadIdx.x, lane = tid&63, w = tid>>6;
  const int wm = w>>1, wn = w&1;
  const int l16 = lane&15, lq = lane>>4;
  f32x4 acc[2][2] = {};
  const int srow = tid>>2, scol = (tid&3)*8;
  for (int c0=0;c0<256;c0+=32){
    *(uint4*)&at[srow][scol] = *(const uint4*)&x[(size_t)(m0+srow)*256 + c0 + scol];
    *(uint4*)&bt[srow][scol] = *(const uint4*)&W[(size_t)(j0+srow)*256 + c0 + scol];
    __syncthreads();
    s16x8 af[2], bfr[2];
    #pragma unroll
    for(int mf=0;mf<2;mf++) af[mf]  = ld_frag(&at[wm*32+mf*16+l16][lq*4]);
    #pragma unroll
    for(int nf=0;nf<2;nf++) bfr[nf] = ld_frag(&bt[wn*32+nf*16+l16][lq*4]);
    #pragma unroll
    for(int mf=0;mf<2;mf++)
      #pragma unroll
      for(int nf=0;nf<2;nf++)
        acc[mf][nf] = __builtin_amdgcn_mfma_f32_16x16x32_bf16(af[mf], bfr[nf], acc[mf][nf],0,0,0);
    __syncthreads();
  }
  // D layout: col = l16, row = lq*4 + r
  if (!isV){
    #pragma unroll
    for(int mf=0;mf<2;mf++)
      #pragma unroll
      for(int nf=0;nf<2;nf++){
        const int j  = j0 + wn*32 + nf*16 + l16;
        const int hh = j>>6;
        const int kkp = wn*32 + (l16>>2)*8 + nf*4 + (l16&3);   // permuted kk
        #pragma unroll
        for(int r=0;r<4;r++){
          int m = m0 + wm*32 + mf*16 + lq*4 + r;
          int blx = m>>11, n = m&2047;
          kbuf[(size_t)((blx<<3)|hh)*131072 + (size_t)n*64 + kkp] = f2bf(acc[mf][nf][r]);
        }
      }
  } else {
    const int blx = m0>>11;
    #pragma unroll
    for(int mf=0;mf<2;mf++){
      const int nn = (m0&2047) + wm*32 + lq*8 + mf*4;          // permuted n-within-tile
      #pragma unroll
      for(int nf=0;nf<2;nf++){
        const int j  = j0 + wn*32 + nf*16 + l16;
        const int hh = j>>6, kk = j&63;
        uint2 st;
        st.x = pkbf(acc[mf][nf][0], acc[mf][nf][1]);
        st.y = pkbf(acc[mf][nf][2], acc[mf][nf][3]);
        *(uint2*)&vbuf[(size_t)((blx<<3)|hh)*131072 + (size_t)kk*2048 + nn] = st;
      }
    }
  }
}

// ---------------- Kernel 2: fused Q-projection + flash attention ----------------
__global__ __launch_bounds__(256) void attn_kernel(
    const u16* __restrict__ x, const u16* __restrict__ Wq,
    const u16* __restrict__ kb, const u16* __restrict__ vb,
    u16* __restrict__ cat)
{
  const int bhl = blockIdx.y;
  const int bl = bhl>>3, h = bhl&7;
  const u16* xg = x + (size_t)bl*524288;
  const u16* kg = kb + (size_t)bhl*131072;
  const u16* vg = vb + (size_t)bhl*131072;     // [dv][n'] layout
  u16* catp = cat + (size_t)bl*1048576 + h*64;
  const int tid=threadIdx.x, lane=tid&63, w=tid>>6;
  const int l16=lane&15, lq=lane>>4;
  const int n0 = blockIdx.x*128;

  __shared__ __align__(16) u16 kt[2][64][72];
  __shared__ __align__(16) u16 vt[2][64][72];

  // ---- Q on the fly: dq[sub][df], D: col=i(l16), row = df*16+lq*4+r = dk ----
  f32x4 dq[2][4] = {};
  {
    const u16* wqh = Wq + (size_t)h*16384;
    s16x8 xf[2][8];
    #pragma unroll
    for(int sub=0;sub<2;sub++){
      const int row = n0 + w*32 + sub*16 + l16;
      #pragma unroll
      for(int kc8=0;kc8<8;kc8++) xf[sub][kc8] = ld_frag(xg + (size_t)row*256 + kc8*32 + lq*4);
    }
    #pragma unroll
    for(int df=0;df<4;df++)
      #pragma unroll
      for(int kc8=0;kc8<8;kc8++){
        s16x8 wf = ld_frag(wqh + (size_t)(df*16+l16)*256 + kc8*32 + lq*4);
        dq[0][df] = __builtin_amdgcn_mfma_f32_16x16x32_bf16(wf, xf[0][kc8], dq[0][df],0,0,0);
        dq[1][df] = __builtin_amdgcn_mfma_f32_16x16x32_bf16(wf, xf[1][kc8], dq[1][df],0,0,0);
      }
  }
  s16x8 qf[2][2];
  #pragma unroll
  for(int sub=0;sub<2;sub++)
    #pragma unroll
    for(int kc=0;kc<2;kc++){
      union{s16x8 v; u32 u[4];} t;
      t.u[0]=pkbf(dq[sub][2*kc][0],  dq[sub][2*kc][1]);
      t.u[1]=pkbf(dq[sub][2*kc][2],  dq[sub][2*kc][3]);
      t.u[2]=pkbf(dq[sub][2*kc+1][0],dq[sub][2*kc+1][1]);
      t.u[3]=pkbf(dq[sub][2*kc+1][2],dq[sub][2*kc+1][3]);
      qf[sub][kc]=t.v;
    }

  // ---- staging addresses (straight row copies; layouts pre-permuted) ----
  const int srow = tid>>2, sc = (tid&3)*16;
  const u16* kst = kg + (size_t)srow*64 + sc;
  const u16* vst = vg + (size_t)srow*2048 + sc;
  uint4 kr0,kr1,vr0,vr1;
  kr0 = *(const uint4*)(kst);   kr1 = *(const uint4*)(kst+8);
  vr0 = *(const uint4*)(vst);   vr1 = *(const uint4*)(vst+8);
  *(uint4*)&kt[0][srow][sc] = kr0;  *(uint4*)&kt[0][srow][sc+8] = kr1;
  *(uint4*)&vt[0][srow][sc] = vr0;  *(uint4*)&vt[0][srow][sc+8] = vr1;
  __syncthreads();

  const float SCL = 0.125f * 1.44269504088896f;   // scale * log2(e)
  f32x4 oacc[2][4] = {};
  float mrun[2]={-1e30f,-1e30f}, lrun[2]={0.f,0.f};

  for(int t=0;t<32;t++){
    const int cur = t&1;
    if (t<31){
      kr0 = *(const uint4*)(kst + (size_t)(t+1)*4096);
      kr1 = *(const uint4*)(kst + (size_t)(t+1)*4096 + 8);
      vr0 = *(const uint4*)(vst + (size_t)(t+1)*64);
      vr1 = *(const uint4*)(vst + (size_t)(t+1)*64 + 8);
    }
    // ---- S^T = mfma(K, Q): kf shared across both subtiles ----
    f32x4 sacc[2][4] = {};
    #pragma unroll
    for(int jf=0;jf<4;jf++)
      #pragma unroll
      for(int kc=0;kc<2;kc++){
        s16x8 kf = *(const s16x8*)&kt[cur][jf*16+l16][kc*32+lq*8];
        sacc[0][jf]=__builtin_amdgcn_mfma_f32_16x16x32_bf16(kf,qf[0][kc],sacc[0][jf],0,0,0);
        sacc[1][jf]=__builtin_amdgcn_mfma_f32_16x16x32_bf16(kf,qf[1][kc],sacc[1][jf],0,0,0);
      }
    // ---- online softmax (base-2), per subtile ----
    s16x8 pf[2][2];
    #pragma unroll
    for(int sub=0;sub<2;sub++){
      float mloc=-1e30f;
      #pragma unroll
      for(int jf=0;jf<4;jf++)
        #pragma unroll
        for(int r=0;r<4;r++){
          float v2 = sacc[sub][jf][r]*SCL;
          sacc[sub][jf][r]=v2;
          mloc=fmaxf(mloc,v2);
        }
      mloc=fmaxf(mloc,__shfl_xor(mloc,16,64));
      mloc=fmaxf(mloc,__shfl_xor(mloc,32,64));
      const float mnew=fmaxf(mrun[sub],mloc);
      const float alpha=exp2a(mrun[sub]-mnew);
      float rsum=0.f;
      float p[4][4];
      #pragma unroll
      for(int jf=0;jf<4;jf++)
        #pragma unroll
        for(int r=0;r<4;r++){
          float e=exp2a(sacc[sub][jf][r]-mnew);
          p[jf][r]=e; rsum+=e;
        }
      rsum+=__shfl_xor(rsum,16,64);
      rsum+=__shfl_xor(rsum,32,64);
      lrun[sub]=lrun[sub]*alpha+rsum;
      mrun[sub]=mnew;
      #pragma unroll
      for(int cf=0;cf<4;cf++) oacc[sub][cf]*=alpha;
      #pragma unroll
      for(int kc=0;kc<2;kc++){
        union{s16x8 v; u32 u[4];} tt;
        tt.u[0]=pkbf(p[2*kc][0],  p[2*kc][1]);
        tt.u[1]=pkbf(p[2*kc][2],  p[2*kc][3]);
        tt.u[2]=pkbf(p[2*kc+1][0],p[2*kc+1][1]);
        tt.u[3]=pkbf(p[2*kc+1][2],p[2*kc+1][3]);
        pf[sub][kc]=tt.v;
      }
    }
    // ---- O^T += mfma(V^T, P^T): vf shared across subtiles ----
    #pragma unroll
    for(int cf=0;cf<4;cf++)
      #pragma unroll
      for(int kc=0;kc<2;kc++){
        s16x8 vf = *(const s16x8*)&vt[cur][cf*16+l16][kc*32+lq*8];
        oacc[0][cf]=__builtin_amdgcn_mfma_f32_16x16x32_bf16(vf,pf[0][kc],oacc[0][cf],0,0,0);
        oacc[1][cf]=__builtin_amdgcn_mfma_f32_16x16x32_bf16(vf,pf[1][kc],oacc[1][cf],0,0,0);
      }
    if (t<31){
      const int nb = cur^1;
      *(uint4*)&kt[nb][srow][sc]   = kr0;  *(uint4*)&kt[nb][srow][sc+8] = kr1;
      *(uint4*)&vt[nb][srow][sc]   = vr0;  *(uint4*)&vt[nb][srow][sc+8] = vr1;
    }
    __syncthreads();
  }
  // ---- epilogue: packed stores ----
  #pragma unroll
  for(int sub=0;sub<2;sub++){
    const float rinv = 1.f/lrun[sub];
    const int n = n0 + w*32 + sub*16 + l16;
    #pragma unroll
    for(int cf=0;cf<4;cf++){
      uint2 st;
      st.x = pkbf(oacc[sub][cf][0]*rinv, oacc[sub][cf][1]*rinv);
      st.y = pkbf(oacc[sub][cf][2]*rinv, oacc[sub][cf][3]*rinv);
      *(uint2*)(catp + (size_t)n*512 + cf*16 + lq*4) = st;
    }
  }
}

// ---------------- Kernel 3: output projection + BN + LeakyReLU (fp32 out) ----------------
__global__ __launch_bounds__(256) void proj_kernel(
    const u16* __restrict__ cat, const u16* __restrict__ Wp,
    const float* __restrict__ gamma, const float* __restrict__ beta,
    const float* __restrict__ mean,  const float* __restrict__ var,
    float* __restrict__ out)
{
  const int m0 = blockIdx.x*64, j0 = blockIdx.y*64;
  __shared__ u16 at[64][40];
  __shared__ u16 bt[64][40];
  const int tid=threadIdx.x, lane=tid&63, w=tid>>6;
  const int wm=w>>1, wn=w&1, l16=lane&15, lq=lane>>4;
  f32x4 acc[2][2]={};
  const int srow=tid>>2, scol=(tid&3)*8;
  for(int c0=0;c0<512;c0+=32){
    *(uint4*)&at[srow][scol] = *(const uint4*)&cat[(size_t)(m0+srow)*512 + c0+scol];
    *(uint4*)&bt[srow][scol] = *(const uint4*)&Wp[(size_t)(j0+srow)*512 + c0+scol];
    __syncthreads();
    s16x8 af[2],bfr[2];
    #pragma unroll
    for(int mf=0;mf<2;mf++) af[mf]=ld_frag(&at[wm*32+mf*16+l16][lq*4]);
    #pragma unroll
    for(int nf=0;nf<2;nf++) bfr[nf]=ld_frag(&bt[wn*32+nf*16+l16][lq*4]);
    #pragma unroll
    for(int mf=0;mf<2;mf++)
      #pragma unroll
      for(int nf=0;nf<2;nf++)
        acc[mf][nf]=__builtin_amdgcn_mfma_f32_16x16x32_bf16(af[mf],bfr[nf],acc[mf][nf],0,0,0);
    __syncthreads();
  }
  #pragma unroll
  for(int nf=0;nf<2;nf++){
    const int co = j0 + wn*32 + nf*16 + l16;
    const float g=gamma[co], be=beta[co], mu=mean[co], va=var[co];
    const float a  = g * rsqrtf(va + 1e-5f);
    const float b2 = be - mu*a;
    #pragma unroll
    for(int mf=0;mf<2;mf++)
      #pragma unroll
      for(int r=0;r<4;r++){
        int m = m0 + wm*32 + mf*16 + lq*4 + r;
        float y = acc[mf][nf][r]*a + b2;
        y = (y>=0.f)? y : 0.01f*y;
        out[(size_t)m*256 + co] = y;
      }
  }
}

extern "C" void kernel_launch(void* const* d_in, const int* in_sizes, int n_in,
                              void* d_out, int out_size, void* d_ws, size_t ws_size,
                              hipStream_t stream)
{
  const float* x  = (const float*)d_in[0];
  const float* Wq = (const float*)d_in[1];
  const float* Wk = (const float*)d_in[2];
  const float* Wv = (const float*)d_in[3];
  const float* Wp = (const float*)d_in[4];
  const float* g  = (const float*)d_in[5];
  const float* be = (const float*)d_in[6];
  const float* mu = (const float*)d_in[7];
  const float* va = (const float*)d_in[8];

  u16* ws   = (u16*)d_ws;
  u16* x16  = ws;                         // 4,194,304 elems (8 MiB)
  u16* wq16 = ws + 4194304;
  u16* wk16 = ws + 4325376;
  u16* wv16 = ws + 4456448;
  u16* wp16 = ws + 4587520;
  u16* kb   = ws + 4718592;               // 8 MiB (32 bh * 2048 * 64)
  u16* vb   = ws + 8912896;               // 8 MiB
  u16* cat  = ws + 13107200;              // 16 MiB -> total ~41 MiB

  cvt_kernel<<<4096, 256, 0, stream>>>(x,  x16,  1048576);
  cvt_kernel<<<128,  256, 0, stream>>>(Wq, wq16, 32768);
  cvt_kernel<<<128,  256, 0, stream>>>(Wk, wk16, 32768);
  cvt_kernel<<<128,  256, 0, stream>>>(Wv, wv16, 32768);
  cvt_kernel<<<128,  256, 0, stream>>>(Wp, wp16, 32768);

  for (int half = 0; half < 2; ++half){
    const u16* xh = x16 + (size_t)half*2097152;
    u16* cath = cat + (size_t)half*4194304;
    kv_kernel<<<dim3(128,8,2), dim3(256), 0, stream>>>(xh, wk16, wv16, kb, vb);
    attn_kernel<<<dim3(16,32), dim3(256), 0, stream>>>(xh, wq16, kb, vb, cath);
  }
  proj_kernel<<<dim3(256,4), dim3(256), 0, stream>>>(cat, wp16, g, be, mu, va, (float*)d_out);
}

// Round 5
// 214.268 us; speedup vs baseline: 1.6266x; 1.0915x over previous
//
#include <hip/hip_runtime.h>
#include <hip/hip_bf16.h>

typedef unsigned short u16;
typedef unsigned int u32;
typedef float  f32x4 __attribute__((ext_vector_type(4)));
typedef short  s16x8 __attribute__((ext_vector_type(8)));

#define DEV static __device__ __forceinline__

DEV u16 f2bf(float f){ union{float f; unsigned int i;} c; c.f=f; unsigned int i=c.i;
                       return (u16)((i + 0x7FFFu + ((i>>16)&1u))>>16); }

// packed 2x f32 -> bf16x2 (v_cvt_pk_bf16_f32), low word = a
DEV u32 pkbf(float a, float b){
  union{ __hip_bfloat162 h; u32 u; } c;
  c.h = __float22bfloat162_rn(make_float2(a, b));
  return c.u;
}

DEV float exp2a(float x){
#if __has_builtin(__builtin_amdgcn_exp2f)
  return __builtin_amdgcn_exp2f(x);
#else
  return exp2f(x);
#endif
}

// 16x16x32 A/B fragment, plain layout: 4 contiguous bf16 at p, 4 at p+16.
// Same k-map mu(lq,e) for all operands (incl. D->B repacks) -> permutation-safe.
DEV s16x8 ld_frag(const u16* p){
  union{ s16x8 v; uint2 u[2]; } r;
  r.u[0] = *(const uint2*)(p);
  r.u[1] = *(const uint2*)(p+16);
  return r.v;
}

// ---------------- Kernel 0: fp32 -> bf16 ----------------
__global__ __launch_bounds__(256) void cvt_kernel(const float* __restrict__ src,
                                                  u16* __restrict__ dst, int n4)
{
  int i = blockIdx.x*256 + threadIdx.x;
  if (i >= n4) return;
  float4 v = *(const float4*)(src + (size_t)i*4);
  ushort4 o;
  o.x = f2bf(v.x); o.y = f2bf(v.y); o.z = f2bf(v.z); o.w = f2bf(v.w);
  *(ushort4*)(dst + (size_t)i*4) = o;
}

// ---------------- Kernel 1: K/V projection ----------------
// K stored [bh][n][kk'] (kk' fragment-permuted); V stored transposed
// [bh][dv][n'] (n' fragment-permuted within each 64-tile).
__global__ __launch_bounds__(256) void kv_kernel(
    const u16* __restrict__ x, const u16* __restrict__ Wk,
    const u16* __restrict__ Wv, u16* __restrict__ kbuf, u16* __restrict__ vbuf)
{
  const int isV = blockIdx.z;
  const u16* W = isV ? Wv : Wk;
  const int m0 = blockIdx.x*64, j0 = blockIdx.y*64;
  __shared__ u16 at[64][40];
  __shared__ u16 bt[64][40];
  const int tid = threadIdx.x, lane = tid&63, w = tid>>6;
  const int wm = w>>1, wn = w&1;
  const int l16 = lane&15, lq = lane>>4;
  f32x4 acc[2][2] = {};
  const int srow = tid>>2, scol = (tid&3)*8;
  for (int c0=0;c0<256;c0+=32){
    *(uint4*)&at[srow][scol] = *(const uint4*)&x[(size_t)(m0+srow)*256 + c0 + scol];
    *(uint4*)&bt[srow][scol] = *(const uint4*)&W[(size_t)(j0+srow)*256 + c0 + scol];
    __syncthreads();
    s16x8 af[2], bfr[2];
    #pragma unroll
    for(int mf=0;mf<2;mf++) af[mf]  = ld_frag(&at[wm*32+mf*16+l16][lq*4]);
    #pragma unroll
    for(int nf=0;nf<2;nf++) bfr[nf] = ld_frag(&bt[wn*32+nf*16+l16][lq*4]);
    #pragma unroll
    for(int mf=0;mf<2;mf++)
      #pragma unroll
      for(int nf=0;nf<2;nf++)
        acc[mf][nf] = __builtin_amdgcn_mfma_f32_16x16x32_bf16(af[mf], bfr[nf], acc[mf][nf],0,0,0);
    __syncthreads();
  }
  // D layout: col = l16, row = lq*4 + r
  if (!isV){
    #pragma unroll
    for(int mf=0;mf<2;mf++)
      #pragma unroll
      for(int nf=0;nf<2;nf++){
        const int j  = j0 + wn*32 + nf*16 + l16;
        const int hh = j>>6;
        const int kkp = wn*32 + (l16>>2)*8 + nf*4 + (l16&3);   // permuted kk
        #pragma unroll
        for(int r=0;r<4;r++){
          int m = m0 + wm*32 + mf*16 + lq*4 + r;
          int blx = m>>11, n = m&2047;
          kbuf[(size_t)((blx<<3)|hh)*131072 + (size_t)n*64 + kkp] = f2bf(acc[mf][nf][r]);
        }
      }
  } else {
    const int blx = m0>>11;
    #pragma unroll
    for(int mf=0;mf<2;mf++){
      const int nn = (m0&2047) + wm*32 + lq*8 + mf*4;          // permuted n-within-tile
      #pragma unroll
      for(int nf=0;nf<2;nf++){
        const int j  = j0 + wn*32 + nf*16 + l16;
        const int hh = j>>6, kk = j&63;
        uint2 st;
        st.x = pkbf(acc[mf][nf][0], acc[mf][nf][1]);
        st.y = pkbf(acc[mf][nf][2], acc[mf][nf][3]);
        *(uint2*)&vbuf[(size_t)((blx<<3)|hh)*131072 + (size_t)kk*2048 + nn] = st;
      }
    }
  }
}

// ---------------- Kernel 2: fused Q-projection + flash attention ----------------
// 64 q-rows per block; scale folded into Q; defer-max rescale (THR=8, base-2).
__global__ __launch_bounds__(256) void attn_kernel(
    const u16* __restrict__ x, const u16* __restrict__ Wq,
    const u16* __restrict__ kb, const u16* __restrict__ vb,
    u16* __restrict__ cat)
{
  const int bhl = blockIdx.y;
  const int bl = bhl>>3, h = bhl&7;
  const u16* xg = x + (size_t)bl*524288;
  const u16* kg = kb + (size_t)bhl*131072;
  const u16* vg = vb + (size_t)bhl*131072;     // [dv][n'] layout
  u16* catp = cat + (size_t)bl*1048576 + h*64;
  const int tid=threadIdx.x, lane=tid&63, w=tid>>6;
  const int l16=lane&15, lq=lane>>4;
  const int n0 = blockIdx.x*64;

  __shared__ __align__(16) u16 kt[2][64][72];
  __shared__ __align__(16) u16 vt[2][64][72];

  // ---- Q on the fly: D_q col=i(l16), row = df*16+lq*4+r = dk; scale folded ----
  s16x8 qf[2];
  {
    const u16* wqh = Wq + (size_t)h*16384;
    const int row = n0 + w*16 + l16;
    s16x8 xf[8];
    #pragma unroll
    for(int kc8=0;kc8<8;kc8++) xf[kc8] = ld_frag(xg + (size_t)row*256 + kc8*32 + lq*4);
    f32x4 dq[4] = {};
    #pragma unroll
    for(int df=0;df<4;df++)
      #pragma unroll
      for(int kc8=0;kc8<8;kc8++){
        s16x8 wf = ld_frag(wqh + (size_t)(df*16+l16)*256 + kc8*32 + lq*4);
        dq[df] = __builtin_amdgcn_mfma_f32_16x16x32_bf16(wf, xf[kc8], dq[df],0,0,0);
      }
    const float SCL = 0.125f * 1.44269504088896f;   // attn scale * log2(e)
    #pragma unroll
    for(int kc=0;kc<2;kc++){
      union{s16x8 v; u32 u[4];} t;
      t.u[0]=pkbf(dq[2*kc][0]*SCL,  dq[2*kc][1]*SCL);
      t.u[1]=pkbf(dq[2*kc][2]*SCL,  dq[2*kc][3]*SCL);
      t.u[2]=pkbf(dq[2*kc+1][0]*SCL,dq[2*kc+1][1]*SCL);
      t.u[3]=pkbf(dq[2*kc+1][2]*SCL,dq[2*kc+1][3]*SCL);
      qf[kc]=t.v;
    }
  }

  // ---- staging (straight row copies; layouts pre-permuted) ----
  const int srow = tid>>2, sc = (tid&3)*16;
  const u16* kst = kg + (size_t)srow*64 + sc;
  const u16* vst = vg + (size_t)srow*2048 + sc;
  uint4 kr0,kr1,vr0,vr1;
  kr0 = *(const uint4*)(kst);   kr1 = *(const uint4*)(kst+8);
  vr0 = *(const uint4*)(vst);   vr1 = *(const uint4*)(vst+8);
  *(uint4*)&kt[0][srow][sc] = kr0;  *(uint4*)&kt[0][srow][sc+8] = kr1;
  *(uint4*)&vt[0][srow][sc] = vr0;  *(uint4*)&vt[0][srow][sc+8] = vr1;
  __syncthreads();

  f32x4 oacc[4] = {};
  float mrun=-1e30f, lrun=0.f;

  for(int t=0;t<32;t++){
    const int cur = t&1;
    if (t<31){
      kr0 = *(const uint4*)(kst + (size_t)(t+1)*4096);
      kr1 = *(const uint4*)(kst + (size_t)(t+1)*4096 + 8);
      vr0 = *(const uint4*)(vst + (size_t)(t+1)*64);
      vr1 = *(const uint4*)(vst + (size_t)(t+1)*64 + 8);
    }
    // ---- S^T = mfma(K, Q) (pre-scaled) ----
    f32x4 sacc[4] = {};
    #pragma unroll
    for(int jf=0;jf<4;jf++)
      #pragma unroll
      for(int kc=0;kc<2;kc++){
        s16x8 kf = *(const s16x8*)&kt[cur][jf*16+l16][kc*32+lq*8];
        sacc[jf]=__builtin_amdgcn_mfma_f32_16x16x32_bf16(kf,qf[kc],sacc[jf],0,0,0);
      }
    // ---- online softmax (base-2), defer-max ----
    float mloc=-1e30f;
    #pragma unroll
    for(int jf=0;jf<4;jf++)
      #pragma unroll
      for(int r=0;r<4;r++) mloc=fmaxf(mloc,sacc[jf][r]);
    mloc=fmaxf(mloc,__shfl_xor(mloc,16,64));
    mloc=fmaxf(mloc,__shfl_xor(mloc,32,64));
    if (!__all(mloc - mrun <= 8.0f)){
      const float mnew=fmaxf(mrun,mloc);
      const float alpha=exp2a(mrun-mnew);
      #pragma unroll
      for(int cf=0;cf<4;cf++) oacc[cf]*=alpha;
      lrun*=alpha;
      mrun=mnew;
    }
    float rsum=0.f;
    float p[4][4];
    #pragma unroll
    for(int jf=0;jf<4;jf++)
      #pragma unroll
      for(int r=0;r<4;r++){
        float e=exp2a(sacc[jf][r]-mrun);
        p[jf][r]=e; rsum+=e;
      }
    rsum+=__shfl_xor(rsum,16,64);
    rsum+=__shfl_xor(rsum,32,64);
    lrun+=rsum;
    s16x8 pf[2];
    #pragma unroll
    for(int kc=0;kc<2;kc++){
      union{s16x8 v; u32 u[4];} tt;
      tt.u[0]=pkbf(p[2*kc][0],  p[2*kc][1]);
      tt.u[1]=pkbf(p[2*kc][2],  p[2*kc][3]);
      tt.u[2]=pkbf(p[2*kc+1][0],p[2*kc+1][1]);
      tt.u[3]=pkbf(p[2*kc+1][2],p[2*kc+1][3]);
      pf[kc]=tt.v;
    }
    // ---- O^T += mfma(V^T, P^T) ----
    #pragma unroll
    for(int cf=0;cf<4;cf++)
      #pragma unroll
      for(int kc=0;kc<2;kc++){
        s16x8 vf = *(const s16x8*)&vt[cur][cf*16+l16][kc*32+lq*8];
        oacc[cf]=__builtin_amdgcn_mfma_f32_16x16x32_bf16(vf,pf[kc],oacc[cf],0,0,0);
      }
    if (t<31){
      const int nb = cur^1;
      *(uint4*)&kt[nb][srow][sc]   = kr0;  *(uint4*)&kt[nb][srow][sc+8] = kr1;
      *(uint4*)&vt[nb][srow][sc]   = vr0;  *(uint4*)&vt[nb][srow][sc+8] = vr1;
    }
    __syncthreads();
  }
  // ---- epilogue ----
  const float rinv = 1.f/lrun;
  const int n = n0 + w*16 + l16;
  #pragma unroll
  for(int cf=0;cf<4;cf++){
    uint2 st;
    st.x = pkbf(oacc[cf][0]*rinv, oacc[cf][1]*rinv);
    st.y = pkbf(oacc[cf][2]*rinv, oacc[cf][3]*rinv);
    *(uint2*)(catp + (size_t)n*512 + cf*16 + lq*4) = st;
  }
}

// ---------------- Kernel 3: output projection + BN + LeakyReLU (fp32 out) ----------------
__global__ __launch_bounds__(256) void proj_kernel(
    const u16* __restrict__ cat, const u16* __restrict__ Wp,
    const float* __restrict__ gamma, const float* __restrict__ beta,
    const float* __restrict__ mean,  const float* __restrict__ var,
    float* __restrict__ out)
{
  const int m0 = blockIdx.x*64, j0 = blockIdx.y*64;
  __shared__ u16 at[64][40];
  __shared__ u16 bt[64][40];
  const int tid=threadIdx.x, lane=tid&63, w=tid>>6;
  const int wm=w>>1, wn=w&1, l16=lane&15, lq=lane>>4;
  f32x4 acc[2][2]={};
  const int srow=tid>>2, scol=(tid&3)*8;
  for(int c0=0;c0<512;c0+=32){
    *(uint4*)&at[srow][scol] = *(const uint4*)&cat[(size_t)(m0+srow)*512 + c0+scol];
    *(uint4*)&bt[srow][scol] = *(const uint4*)&Wp[(size_t)(j0+srow)*512 + c0+scol];
    __syncthreads();
    s16x8 af[2],bfr[2];
    #pragma unroll
    for(int mf=0;mf<2;mf++) af[mf]=ld_frag(&at[wm*32+mf*16+l16][lq*4]);
    #pragma unroll
    for(int nf=0;nf<2;nf++) bfr[nf]=ld_frag(&bt[wn*32+nf*16+l16][lq*4]);
    #pragma unroll
    for(int mf=0;mf<2;mf++)
      #pragma unroll
      for(int nf=0;nf<2;nf++)
        acc[mf][nf]=__builtin_amdgcn_mfma_f32_16x16x32_bf16(af[mf],bfr[nf],acc[mf][nf],0,0,0);
    __syncthreads();
  }
  #pragma unroll
  for(int nf=0;nf<2;nf++){
    const int co = j0 + wn*32 + nf*16 + l16;
    const float g=gamma[co], be=beta[co], mu=mean[co], va=var[co];
    const float a  = g * rsqrtf(va + 1e-5f);
    const float b2 = be - mu*a;
    #pragma unroll
    for(int mf=0;mf<2;mf++)
      #pragma unroll
      for(int r=0;r<4;r++){
        int m = m0 + wm*32 + mf*16 + lq*4 + r;
        float y = acc[mf][nf][r]*a + b2;
        y = (y>=0.f)? y : 0.01f*y;
        out[(size_t)m*256 + co] = y;
      }
  }
}

extern "C" void kernel_launch(void* const* d_in, const int* in_sizes, int n_in,
                              void* d_out, int out_size, void* d_ws, size_t ws_size,
                              hipStream_t stream)
{
  const float* x  = (const float*)d_in[0];
  const float* Wq = (const float*)d_in[1];
  const float* Wk = (const float*)d_in[2];
  const float* Wv = (const float*)d_in[3];
  const float* Wp = (const float*)d_in[4];
  const float* g  = (const float*)d_in[5];
  const float* be = (const float*)d_in[6];
  const float* mu = (const float*)d_in[7];
  const float* va = (const float*)d_in[8];

  u16* ws   = (u16*)d_ws;
  u16* x16  = ws;                         // 4,194,304 elems
  u16* wq16 = ws + 4194304;
  u16* wk16 = ws + 4325376;
  u16* wv16 = ws + 4456448;
  u16* wp16 = ws + 4587520;
  u16* kb   = ws + 4718592;

  cvt_kernel<<<4096, 256, 0, stream>>>(x,  x16,  1048576);
  cvt_kernel<<<128,  256, 0, stream>>>(Wq, wq16, 32768);
  cvt_kernel<<<128,  256, 0, stream>>>(Wk, wk16, 32768);
  cvt_kernel<<<128,  256, 0, stream>>>(Wv, wv16, 32768);
  cvt_kernel<<<128,  256, 0, stream>>>(Wp, wp16, 32768);

  // full path: kb(16MiB) + vb(16MiB) + cat(16MiB) after the 9.4MiB prefix
  const size_t full_elems = 4718592ull + 8388608ull*3ull;   // 29,884,416 u16
  if (ws_size >= full_elems*2ull){
    u16* vb  = kb + 8388608;
    u16* cat = vb + 8388608;
    kv_kernel<<<dim3(256,8,2), dim3(256), 0, stream>>>(x16, wk16, wv16, kb, vb);
    attn_kernel<<<dim3(32,64), dim3(256), 0, stream>>>(x16, wq16, kb, vb, cat);
    proj_kernel<<<dim3(256,4), dim3(256), 0, stream>>>(cat, wp16, g, be, mu, va, (float*)d_out);
  } else {
    u16* vb  = kb + 4194304;
    u16* cat = vb + 4194304;
    for (int half = 0; half < 2; ++half){
      const u16* xh = x16 + (size_t)half*2097152;
      u16* cath = cat + (size_t)half*4194304;
      kv_kernel<<<dim3(128,8,2), dim3(256), 0, stream>>>(xh, wk16, wv16, kb, vb);
      attn_kernel<<<dim3(32,32), dim3(256), 0, stream>>>(xh, wq16, kb, vb, cath);
    }
    proj_kernel<<<dim3(256,4), dim3(256), 0, stream>>>(cat, wp16, g, be, mu, va, (float*)d_out);
  }
}

// Round 6
// 193.492 us; speedup vs baseline: 1.8013x; 1.1074x over previous
//
#include <hip/hip_runtime.h>
#include <hip/hip_bf16.h>

typedef unsigned short u16;
typedef unsigned int u32;
typedef float  f32x4 __attribute__((ext_vector_type(4)));
typedef short  s16x8 __attribute__((ext_vector_type(8)));

#define DEV static __device__ __forceinline__

DEV u16 f2bf(float f){ union{float f; unsigned int i;} c; c.f=f; unsigned int i=c.i;
                       return (u16)((i + 0x7FFFu + ((i>>16)&1u))>>16); }

// packed 2x f32 -> bf16x2 (v_cvt_pk_bf16_f32), low word = a
DEV u32 pkbf(float a, float b){
  union{ __hip_bfloat162 h; u32 u; } c;
  c.h = __float22bfloat162_rn(make_float2(a, b));
  return c.u;
}

DEV float exp2a(float x){
#if __has_builtin(__builtin_amdgcn_exp2f)
  return __builtin_amdgcn_exp2f(x);
#else
  return exp2f(x);
#endif
}

// 16x16x32 A/B fragment, plain layout: 4 contiguous bf16 at p, 4 at p+16.
// Same k-map mu(lq,e) for all operands (incl. D->B repacks) -> permutation-safe.
DEV s16x8 ld_frag(const u16* p){
  union{ s16x8 v; uint2 u[2]; } r;
  r.u[0] = *(const uint2*)(p);
  r.u[1] = *(const uint2*)(p+16);
  return r.v;
}

// ---------------- Kernel 0: fp32 -> bf16 ----------------
__global__ __launch_bounds__(256) void cvt_kernel(const float* __restrict__ src,
                                                  u16* __restrict__ dst, int n4)
{
  int i = blockIdx.x*256 + threadIdx.x;
  if (i >= n4) return;
  float4 v = *(const float4*)(src + (size_t)i*4);
  ushort4 o;
  o.x = f2bf(v.x); o.y = f2bf(v.y); o.z = f2bf(v.z); o.w = f2bf(v.w);
  *(ushort4*)(dst + (size_t)i*4) = o;
}

// ---------------- Kernel 1: K/V projection ----------------
// K stored [bh][n][kk'] (kk' fragment-permuted); V stored transposed
// [bh][dv][n'] (n' fragment-permuted within each 64-tile).
__global__ __launch_bounds__(256) void kv_kernel(
    const u16* __restrict__ x, const u16* __restrict__ Wk,
    const u16* __restrict__ Wv, u16* __restrict__ kbuf, u16* __restrict__ vbuf)
{
  const int isV = blockIdx.z;
  const u16* W = isV ? Wv : Wk;
  const int m0 = blockIdx.x*64, j0 = blockIdx.y*64;
  __shared__ u16 at[64][40];
  __shared__ u16 bt[64][40];
  const int tid = threadIdx.x, lane = tid&63, w = tid>>6;
  const int wm = w>>1, wn = w&1;
  const int l16 = lane&15, lq = lane>>4;
  f32x4 acc[2][2] = {};
  const int srow = tid>>2, scol = (tid&3)*8;
  for (int c0=0;c0<256;c0+=32){
    *(uint4*)&at[srow][scol] = *(const uint4*)&x[(size_t)(m0+srow)*256 + c0 + scol];
    *(uint4*)&bt[srow][scol] = *(const uint4*)&W[(size_t)(j0+srow)*256 + c0 + scol];
    __syncthreads();
    s16x8 af[2], bfr[2];
    #pragma unroll
    for(int mf=0;mf<2;mf++) af[mf]  = ld_frag(&at[wm*32+mf*16+l16][lq*4]);
    #pragma unroll
    for(int nf=0;nf<2;nf++) bfr[nf] = ld_frag(&bt[wn*32+nf*16+l16][lq*4]);
    #pragma unroll
    for(int mf=0;mf<2;mf++)
      #pragma unroll
      for(int nf=0;nf<2;nf++)
        acc[mf][nf] = __builtin_amdgcn_mfma_f32_16x16x32_bf16(af[mf], bfr[nf], acc[mf][nf],0,0,0);
    __syncthreads();
  }
  // D layout: col = l16, row = lq*4 + r
  if (!isV){
    #pragma unroll
    for(int mf=0;mf<2;mf++)
      #pragma unroll
      for(int nf=0;nf<2;nf++){
        const int j  = j0 + wn*32 + nf*16 + l16;
        const int hh = j>>6;
        const int kkp = wn*32 + (l16>>2)*8 + nf*4 + (l16&3);   // permuted kk
        #pragma unroll
        for(int r=0;r<4;r++){
          int m = m0 + wm*32 + mf*16 + lq*4 + r;
          int blx = m>>11, n = m&2047;
          kbuf[(size_t)((blx<<3)|hh)*131072 + (size_t)n*64 + kkp] = f2bf(acc[mf][nf][r]);
        }
      }
  } else {
    const int blx = m0>>11;
    #pragma unroll
    for(int mf=0;mf<2;mf++){
      const int nn = (m0&2047) + wm*32 + lq*8 + mf*4;          // permuted n-within-tile
      #pragma unroll
      for(int nf=0;nf<2;nf++){
        const int j  = j0 + wn*32 + nf*16 + l16;
        const int hh = j>>6, kk = j&63;
        uint2 st;
        st.x = pkbf(acc[mf][nf][0], acc[mf][nf][1]);
        st.y = pkbf(acc[mf][nf][2], acc[mf][nf][3]);
        *(uint2*)&vbuf[(size_t)((blx<<3)|hh)*131072 + (size_t)kk*2048 + nn] = st;
      }
    }
  }
}

// ---------------- Kernel 2: fused Q-projection + flash attention ----------------
// 128 q-rows per block (2 subtiles/wave); XCD-swizzled 1-D grid; scale folded
// into Q; defer-max rescale (THR=8, base-2).
__global__ __launch_bounds__(256) void attn_kernel(
    const u16* __restrict__ x, const u16* __restrict__ Wq,
    const u16* __restrict__ kb, const u16* __restrict__ vb,
    u16* __restrict__ cat, int bh_per_xcd)
{
  const int lin = blockIdx.x;
  const int xcd = lin & 7, slot = lin >> 3;
  const int bhl = xcd*bh_per_xcd + (slot>>4);     // 16 q-tiles per bh
  const int n0  = (slot & 15) * 128;
  const int bl = bhl>>3, h = bhl&7;
  const u16* xg = x + (size_t)bl*524288;
  const u16* kg = kb + (size_t)bhl*131072;
  const u16* vg = vb + (size_t)bhl*131072;     // [dv][n'] layout
  u16* catp = cat + (size_t)bl*1048576 + h*64;
  const int tid=threadIdx.x, lane=tid&63, w=tid>>6;
  const int l16=lane&15, lq=lane>>4;

  __shared__ __align__(16) u16 kt[2][64][72];
  __shared__ __align__(16) u16 vt[2][64][72];

  // ---- Q on the fly for 2 subtiles; scale folded into qf ----
  s16x8 qf[2][2];
  {
    const u16* wqh = Wq + (size_t)h*16384;
    s16x8 xf[2][8];
    #pragma unroll
    for(int sub=0;sub<2;sub++){
      const int row = n0 + w*32 + sub*16 + l16;
      #pragma unroll
      for(int kc8=0;kc8<8;kc8++) xf[sub][kc8] = ld_frag(xg + (size_t)row*256 + kc8*32 + lq*4);
    }
    f32x4 dq[2][4] = {};
    #pragma unroll
    for(int df=0;df<4;df++)
      #pragma unroll
      for(int kc8=0;kc8<8;kc8++){
        s16x8 wf = ld_frag(wqh + (size_t)(df*16+l16)*256 + kc8*32 + lq*4);
        dq[0][df] = __builtin_amdgcn_mfma_f32_16x16x32_bf16(wf, xf[0][kc8], dq[0][df],0,0,0);
        dq[1][df] = __builtin_amdgcn_mfma_f32_16x16x32_bf16(wf, xf[1][kc8], dq[1][df],0,0,0);
      }
    const float SCL = 0.125f * 1.44269504088896f;   // attn scale * log2(e)
    #pragma unroll
    for(int sub=0;sub<2;sub++)
      #pragma unroll
      for(int kc=0;kc<2;kc++){
        union{s16x8 v; u32 u[4];} t;
        t.u[0]=pkbf(dq[sub][2*kc][0]*SCL,  dq[sub][2*kc][1]*SCL);
        t.u[1]=pkbf(dq[sub][2*kc][2]*SCL,  dq[sub][2*kc][3]*SCL);
        t.u[2]=pkbf(dq[sub][2*kc+1][0]*SCL,dq[sub][2*kc+1][1]*SCL);
        t.u[3]=pkbf(dq[sub][2*kc+1][2]*SCL,dq[sub][2*kc+1][3]*SCL);
        qf[sub][kc]=t.v;
      }
  }

  // ---- staging (straight row copies; layouts pre-permuted) ----
  const int srow = tid>>2, sc = (tid&3)*16;
  const u16* kst = kg + (size_t)srow*64 + sc;
  const u16* vst = vg + (size_t)srow*2048 + sc;
  uint4 kr0,kr1,vr0,vr1;
  kr0 = *(const uint4*)(kst);   kr1 = *(const uint4*)(kst+8);
  vr0 = *(const uint4*)(vst);   vr1 = *(const uint4*)(vst+8);
  *(uint4*)&kt[0][srow][sc] = kr0;  *(uint4*)&kt[0][srow][sc+8] = kr1;
  *(uint4*)&vt[0][srow][sc] = vr0;  *(uint4*)&vt[0][srow][sc+8] = vr1;
  __syncthreads();

  f32x4 oacc[2][4] = {};
  float mrun[2]={-1e30f,-1e30f}, lrun[2]={0.f,0.f};

  for(int t=0;t<32;t++){
    const int cur = t&1;
    if (t<31){
      kr0 = *(const uint4*)(kst + (size_t)(t+1)*4096);
      kr1 = *(const uint4*)(kst + (size_t)(t+1)*4096 + 8);
      vr0 = *(const uint4*)(vst + (size_t)(t+1)*64);
      vr1 = *(const uint4*)(vst + (size_t)(t+1)*64 + 8);
    }
    // ---- S^T = mfma(K, Q), kf shared across subtiles ----
    f32x4 sacc[2][4] = {};
    #pragma unroll
    for(int jf=0;jf<4;jf++)
      #pragma unroll
      for(int kc=0;kc<2;kc++){
        s16x8 kf = *(const s16x8*)&kt[cur][jf*16+l16][kc*32+lq*8];
        sacc[0][jf]=__builtin_amdgcn_mfma_f32_16x16x32_bf16(kf,qf[0][kc],sacc[0][jf],0,0,0);
        sacc[1][jf]=__builtin_amdgcn_mfma_f32_16x16x32_bf16(kf,qf[1][kc],sacc[1][jf],0,0,0);
      }
    // ---- online softmax (base-2), defer-max, per subtile ----
    s16x8 pf[2][2];
    #pragma unroll
    for(int sub=0;sub<2;sub++){
      float mloc=-1e30f;
      #pragma unroll
      for(int jf=0;jf<4;jf++)
        #pragma unroll
        for(int r=0;r<4;r++) mloc=fmaxf(mloc,sacc[sub][jf][r]);
      mloc=fmaxf(mloc,__shfl_xor(mloc,16,64));
      mloc=fmaxf(mloc,__shfl_xor(mloc,32,64));
      if (!__all(mloc - mrun[sub] <= 8.0f)){
        const float mnew=fmaxf(mrun[sub],mloc);
        const float alpha=exp2a(mrun[sub]-mnew);
        #pragma unroll
        for(int cf=0;cf<4;cf++) oacc[sub][cf]*=alpha;
        lrun[sub]*=alpha;
        mrun[sub]=mnew;
      }
      float rsum=0.f;
      float p[4][4];
      #pragma unroll
      for(int jf=0;jf<4;jf++)
        #pragma unroll
        for(int r=0;r<4;r++){
          float e=exp2a(sacc[sub][jf][r]-mrun[sub]);
          p[jf][r]=e; rsum+=e;
        }
      rsum+=__shfl_xor(rsum,16,64);
      rsum+=__shfl_xor(rsum,32,64);
      lrun[sub]+=rsum;
      #pragma unroll
      for(int kc=0;kc<2;kc++){
        union{s16x8 v; u32 u[4];} tt;
        tt.u[0]=pkbf(p[2*kc][0],  p[2*kc][1]);
        tt.u[1]=pkbf(p[2*kc][2],  p[2*kc][3]);
        tt.u[2]=pkbf(p[2*kc+1][0],p[2*kc+1][1]);
        tt.u[3]=pkbf(p[2*kc+1][2],p[2*kc+1][3]);
        pf[sub][kc]=tt.v;
      }
    }
    // ---- O^T += mfma(V^T, P^T), vf shared across subtiles ----
    #pragma unroll
    for(int cf=0;cf<4;cf++)
      #pragma unroll
      for(int kc=0;kc<2;kc++){
        s16x8 vf = *(const s16x8*)&vt[cur][cf*16+l16][kc*32+lq*8];
        oacc[0][cf]=__builtin_amdgcn_mfma_f32_16x16x32_bf16(vf,pf[0][kc],oacc[0][cf],0,0,0);
        oacc[1][cf]=__builtin_amdgcn_mfma_f32_16x16x32_bf16(vf,pf[1][kc],oacc[1][cf],0,0,0);
      }
    if (t<31){
      const int nb = cur^1;
      *(uint4*)&kt[nb][srow][sc]   = kr0;  *(uint4*)&kt[nb][srow][sc+8] = kr1;
      *(uint4*)&vt[nb][srow][sc]   = vr0;  *(uint4*)&vt[nb][srow][sc+8] = vr1;
    }
    __syncthreads();
  }
  // ---- epilogue: packed stores ----
  #pragma unroll
  for(int sub=0;sub<2;sub++){
    const float rinv = 1.f/lrun[sub];
    const int n = n0 + w*32 + sub*16 + l16;
    #pragma unroll
    for(int cf=0;cf<4;cf++){
      uint2 st;
      st.x = pkbf(oacc[sub][cf][0]*rinv, oacc[sub][cf][1]*rinv);
      st.y = pkbf(oacc[sub][cf][2]*rinv, oacc[sub][cf][3]*rinv);
      *(uint2*)(catp + (size_t)n*512 + cf*16 + lq*4) = st;
    }
  }
}

// ---------------- Kernel 3: output projection + BN + LeakyReLU (fp32 out) ----------------
__global__ __launch_bounds__(256) void proj_kernel(
    const u16* __restrict__ cat, const u16* __restrict__ Wp,
    const float* __restrict__ gamma, const float* __restrict__ beta,
    const float* __restrict__ mean,  const float* __restrict__ var,
    float* __restrict__ out)
{
  const int m0 = blockIdx.x*64, j0 = blockIdx.y*64;
  __shared__ u16 at[64][40];
  __shared__ u16 bt[64][40];
  const int tid=threadIdx.x, lane=tid&63, w=tid>>6;
  const int wm=w>>1, wn=w&1, l16=lane&15, lq=lane>>4;
  f32x4 acc[2][2]={};
  const int srow=tid>>2, scol=(tid&3)*8;
  for(int c0=0;c0<512;c0+=32){
    *(uint4*)&at[srow][scol] = *(const uint4*)&cat[(size_t)(m0+srow)*512 + c0+scol];
    *(uint4*)&bt[srow][scol] = *(const uint4*)&Wp[(size_t)(j0+srow)*512 + c0+scol];
    __syncthreads();
    s16x8 af[2],bfr[2];
    #pragma unroll
    for(int mf=0;mf<2;mf++) af[mf]=ld_frag(&at[wm*32+mf*16+l16][lq*4]);
    #pragma unroll
    for(int nf=0;nf<2;nf++) bfr[nf]=ld_frag(&bt[wn*32+nf*16+l16][lq*4]);
    #pragma unroll
    for(int mf=0;mf<2;mf++)
      #pragma unroll
      for(int nf=0;nf<2;nf++)
        acc[mf][nf]=__builtin_amdgcn_mfma_f32_16x16x32_bf16(af[mf],bfr[nf],acc[mf][nf],0,0,0);
    __syncthreads();
  }
  #pragma unroll
  for(int nf=0;nf<2;nf++){
    const int co = j0 + wn*32 + nf*16 + l16;
    const float g=gamma[co], be=beta[co], mu=mean[co], va=var[co];
    const float a  = g * rsqrtf(va + 1e-5f);
    const float b2 = be - mu*a;
    #pragma unroll
    for(int mf=0;mf<2;mf++)
      #pragma unroll
      for(int r=0;r<4;r++){
        int m = m0 + wm*32 + mf*16 + lq*4 + r;
        float y = acc[mf][nf][r]*a + b2;
        y = (y>=0.f)? y : 0.01f*y;
        out[(size_t)m*256 + co] = y;
      }
  }
}

extern "C" void kernel_launch(void* const* d_in, const int* in_sizes, int n_in,
                              void* d_out, int out_size, void* d_ws, size_t ws_size,
                              hipStream_t stream)
{
  const float* x  = (const float*)d_in[0];
  const float* Wq = (const float*)d_in[1];
  const float* Wk = (const float*)d_in[2];
  const float* Wv = (const float*)d_in[3];
  const float* Wp = (const float*)d_in[4];
  const float* g  = (const float*)d_in[5];
  const float* be = (const float*)d_in[6];
  const float* mu = (const float*)d_in[7];
  const float* va = (const float*)d_in[8];

  u16* ws   = (u16*)d_ws;
  u16* x16  = ws;                         // 4,194,304 elems
  u16* wq16 = ws + 4194304;
  u16* wk16 = ws + 4325376;
  u16* wv16 = ws + 4456448;
  u16* wp16 = ws + 4587520;
  u16* kb   = ws + 4718592;

  cvt_kernel<<<4096, 256, 0, stream>>>(x,  x16,  1048576);
  cvt_kernel<<<128,  256, 0, stream>>>(Wq, wq16, 32768);
  cvt_kernel<<<128,  256, 0, stream>>>(Wk, wk16, 32768);
  cvt_kernel<<<128,  256, 0, stream>>>(Wv, wv16, 32768);
  cvt_kernel<<<128,  256, 0, stream>>>(Wp, wp16, 32768);

  // full path: kb(16MiB) + vb(16MiB) + cat(16MiB) after the 9.4MiB prefix
  const size_t full_elems = 4718592ull + 8388608ull*3ull;   // 29,884,416 u16
  if (ws_size >= full_elems*2ull){
    u16* vb  = kb + 8388608;
    u16* cat = vb + 8388608;
    kv_kernel<<<dim3(256,8,2), dim3(256), 0, stream>>>(x16, wk16, wv16, kb, vb);
    attn_kernel<<<dim3(1024), dim3(256), 0, stream>>>(x16, wq16, kb, vb, cat, 8);
    proj_kernel<<<dim3(256,4), dim3(256), 0, stream>>>(cat, wp16, g, be, mu, va, (float*)d_out);
  } else {
    u16* vb  = kb + 4194304;
    u16* cat = vb + 4194304;
    for (int half = 0; half < 2; ++half){
      const u16* xh = x16 + (size_t)half*2097152;
      u16* cath = cat + (size_t)half*4194304;
      kv_kernel<<<dim3(128,8,2), dim3(256), 0, stream>>>(xh, wk16, wv16, kb, vb);
      attn_kernel<<<dim3(512), dim3(256), 0, stream>>>(xh, wq16, kb, vb, cath, 4);
    }
    proj_kernel<<<dim3(256,4), dim3(256), 0, stream>>>(cat, wp16, g, be, mu, va, (float*)d_out);
  }
}

// Round 7
// 185.710 us; speedup vs baseline: 1.8768x; 1.0419x over previous
//
#include <hip/hip_runtime.h>
#include <hip/hip_bf16.h>

typedef unsigned short u16;
typedef unsigned int u32;
typedef float  f32x4 __attribute__((ext_vector_type(4)));
typedef short  s16x8 __attribute__((ext_vector_type(8)));

#define DEV static __device__ __forceinline__

DEV u16 f2bf(float f){ union{float f; unsigned int i;} c; c.f=f; unsigned int i=c.i;
                       return (u16)((i + 0x7FFFu + ((i>>16)&1u))>>16); }

// packed 2x f32 -> bf16x2 (v_cvt_pk_bf16_f32), low word = a
DEV u32 pkbf(float a, float b){
  union{ __hip_bfloat162 h; u32 u; } c;
  c.h = __float22bfloat162_rn(make_float2(a, b));
  return c.u;
}

DEV float exp2a(float x){
#if __has_builtin(__builtin_amdgcn_exp2f)
  return __builtin_amdgcn_exp2f(x);
#else
  return exp2f(x);
#endif
}

// 16x16x32 A/B fragment, plain layout: 4 contiguous bf16 at p, 4 at p+16.
// Same k-map mu(lq,e) for all operands (incl. D->B repacks) -> permutation-safe.
DEV s16x8 ld_frag(const u16* p){
  union{ s16x8 v; uint2 u[2]; } r;
  r.u[0] = *(const uint2*)(p);
  r.u[1] = *(const uint2*)(p+16);
  return r.v;
}

// ---------------- Kernel 0: fp32 -> bf16 ----------------
__global__ __launch_bounds__(256) void cvt_kernel(const float* __restrict__ src,
                                                  u16* __restrict__ dst, int n4)
{
  int i = blockIdx.x*256 + threadIdx.x;
  if (i >= n4) return;
  float4 v = *(const float4*)(src + (size_t)i*4);
  ushort4 o;
  o.x = f2bf(v.x); o.y = f2bf(v.y); o.z = f2bf(v.z); o.w = f2bf(v.w);
  *(ushort4*)(dst + (size_t)i*4) = o;
}

// ---------------- Kernel 1: K/V projection ----------------
// K stored [bh][n][kk'] (kk' fragment-permuted); V stored transposed
// [bh][dv][n'] (n' fragment-permuted within each 64-tile).
__global__ __launch_bounds__(256) void kv_kernel(
    const u16* __restrict__ x, const u16* __restrict__ Wk,
    const u16* __restrict__ Wv, u16* __restrict__ kbuf, u16* __restrict__ vbuf)
{
  const int isV = blockIdx.z;
  const u16* W = isV ? Wv : Wk;
  const int m0 = blockIdx.x*64, j0 = blockIdx.y*64;
  __shared__ u16 at[64][40];
  __shared__ u16 bt[64][40];
  const int tid = threadIdx.x, lane = tid&63, w = tid>>6;
  const int wm = w>>1, wn = w&1;
  const int l16 = lane&15, lq = lane>>4;
  f32x4 acc[2][2] = {};
  const int srow = tid>>2, scol = (tid&3)*8;
  for (int c0=0;c0<256;c0+=32){
    *(uint4*)&at[srow][scol] = *(const uint4*)&x[(size_t)(m0+srow)*256 + c0 + scol];
    *(uint4*)&bt[srow][scol] = *(const uint4*)&W[(size_t)(j0+srow)*256 + c0 + scol];
    __syncthreads();
    s16x8 af[2], bfr[2];
    #pragma unroll
    for(int mf=0;mf<2;mf++) af[mf]  = ld_frag(&at[wm*32+mf*16+l16][lq*4]);
    #pragma unroll
    for(int nf=0;nf<2;nf++) bfr[nf] = ld_frag(&bt[wn*32+nf*16+l16][lq*4]);
    #pragma unroll
    for(int mf=0;mf<2;mf++)
      #pragma unroll
      for(int nf=0;nf<2;nf++)
        acc[mf][nf] = __builtin_amdgcn_mfma_f32_16x16x32_bf16(af[mf], bfr[nf], acc[mf][nf],0,0,0);
    __syncthreads();
  }
  // D layout: col = l16, row = lq*4 + r
  if (!isV){
    #pragma unroll
    for(int mf=0;mf<2;mf++)
      #pragma unroll
      for(int nf=0;nf<2;nf++){
        const int j  = j0 + wn*32 + nf*16 + l16;
        const int hh = j>>6;
        const int kkp = wn*32 + (l16>>2)*8 + nf*4 + (l16&3);   // permuted kk
        #pragma unroll
        for(int r=0;r<4;r++){
          int m = m0 + wm*32 + mf*16 + lq*4 + r;
          int blx = m>>11, n = m&2047;
          kbuf[(size_t)((blx<<3)|hh)*131072 + (size_t)n*64 + kkp] = f2bf(acc[mf][nf][r]);
        }
      }
  } else {
    const int blx = m0>>11;
    #pragma unroll
    for(int mf=0;mf<2;mf++){
      const int nn = (m0&2047) + wm*32 + lq*8 + mf*4;          // permuted n-within-tile
      #pragma unroll
      for(int nf=0;nf<2;nf++){
        const int j  = j0 + wn*32 + nf*16 + l16;
        const int hh = j>>6, kk = j&63;
        uint2 st;
        st.x = pkbf(acc[mf][nf][0], acc[mf][nf][1]);
        st.y = pkbf(acc[mf][nf][2], acc[mf][nf][3]);
        *(uint2*)&vbuf[(size_t)((blx<<3)|hh)*131072 + (size_t)kk*2048 + nn] = st;
      }
    }
  }
}

// ---------------- Kernel 2: fused Q-projection + flash attention ----------------
// 128 q-rows per block (2 subtiles/wave); XCD-swizzled 1-D grid; scale folded
// into Q; lane-local defer-max; deferred l-reduction (epilogue-only shfl).
__global__ __launch_bounds__(256) void attn_kernel(
    const u16* __restrict__ x, const u16* __restrict__ Wq,
    const u16* __restrict__ kb, const u16* __restrict__ vb,
    u16* __restrict__ cat, int bh_per_xcd)
{
  const int lin = blockIdx.x;
  const int xcd = lin & 7, slot = lin >> 3;
  const int bhl = xcd*bh_per_xcd + (slot>>4);     // 16 q-tiles per bh
  const int n0  = (slot & 15) * 128;
  const int bl = bhl>>3, h = bhl&7;
  const u16* xg = x + (size_t)bl*524288;
  const u16* kg = kb + (size_t)bhl*131072;
  const u16* vg = vb + (size_t)bhl*131072;     // [dv][n'] layout
  u16* catp = cat + (size_t)bl*1048576 + h*64;
  const int tid=threadIdx.x, lane=tid&63, w=tid>>6;
  const int l16=lane&15, lq=lane>>4;

  __shared__ __align__(16) u16 kt[2][64][72];
  __shared__ __align__(16) u16 vt[2][64][72];

  // ---- Q on the fly for 2 subtiles; scale folded into qf ----
  s16x8 qf[2][2];
  {
    const u16* wqh = Wq + (size_t)h*16384;
    s16x8 xf[2][8];
    #pragma unroll
    for(int sub=0;sub<2;sub++){
      const int row = n0 + w*32 + sub*16 + l16;
      #pragma unroll
      for(int kc8=0;kc8<8;kc8++) xf[sub][kc8] = ld_frag(xg + (size_t)row*256 + kc8*32 + lq*4);
    }
    f32x4 dq[2][4] = {};
    #pragma unroll
    for(int df=0;df<4;df++)
      #pragma unroll
      for(int kc8=0;kc8<8;kc8++){
        s16x8 wf = ld_frag(wqh + (size_t)(df*16+l16)*256 + kc8*32 + lq*4);
        dq[0][df] = __builtin_amdgcn_mfma_f32_16x16x32_bf16(wf, xf[0][kc8], dq[0][df],0,0,0);
        dq[1][df] = __builtin_amdgcn_mfma_f32_16x16x32_bf16(wf, xf[1][kc8], dq[1][df],0,0,0);
      }
    const float SCL = 0.125f * 1.44269504088896f;   // attn scale * log2(e)
    #pragma unroll
    for(int sub=0;sub<2;sub++)
      #pragma unroll
      for(int kc=0;kc<2;kc++){
        union{s16x8 v; u32 u[4];} t;
        t.u[0]=pkbf(dq[sub][2*kc][0]*SCL,  dq[sub][2*kc][1]*SCL);
        t.u[1]=pkbf(dq[sub][2*kc][2]*SCL,  dq[sub][2*kc][3]*SCL);
        t.u[2]=pkbf(dq[sub][2*kc+1][0]*SCL,dq[sub][2*kc+1][1]*SCL);
        t.u[3]=pkbf(dq[sub][2*kc+1][2]*SCL,dq[sub][2*kc+1][3]*SCL);
        qf[sub][kc]=t.v;
      }
  }

  // ---- staging (straight row copies; layouts pre-permuted) ----
  const int srow = tid>>2, sc = (tid&3)*16;
  const u16* kst = kg + (size_t)srow*64 + sc;
  const u16* vst = vg + (size_t)srow*2048 + sc;
  uint4 kr0,kr1,vr0,vr1;
  kr0 = *(const uint4*)(kst);   kr1 = *(const uint4*)(kst+8);
  vr0 = *(const uint4*)(vst);   vr1 = *(const uint4*)(vst+8);
  *(uint4*)&kt[0][srow][sc] = kr0;  *(uint4*)&kt[0][srow][sc+8] = kr1;
  *(uint4*)&vt[0][srow][sc] = vr0;  *(uint4*)&vt[0][srow][sc+8] = vr1;
  __syncthreads();

  f32x4 oacc[2][4] = {};
  float mrun[2]={-1e30f,-1e30f}, lsum[2]={0.f,0.f};   // lsum is PER-LANE (partial)

  for(int t=0;t<32;t++){
    const int cur = t&1;
    if (t<31){
      kr0 = *(const uint4*)(kst + (size_t)(t+1)*4096);
      kr1 = *(const uint4*)(kst + (size_t)(t+1)*4096 + 8);
      vr0 = *(const uint4*)(vst + (size_t)(t+1)*64);
      vr1 = *(const uint4*)(vst + (size_t)(t+1)*64 + 8);
    }
    // ---- hoisted K fragment reads (back-to-back issue) ----
    s16x8 kf[8];
    #pragma unroll
    for(int jf=0;jf<4;jf++)
      #pragma unroll
      for(int kc=0;kc<2;kc++)
        kf[jf*2+kc] = *(const s16x8*)&kt[cur][jf*16+l16][kc*32+lq*8];
    // ---- S^T = mfma(K, Q), kf shared across subtiles ----
    f32x4 sacc[2][4] = {};
    #pragma unroll
    for(int jf=0;jf<4;jf++)
      #pragma unroll
      for(int kc=0;kc<2;kc++){
        sacc[0][jf]=__builtin_amdgcn_mfma_f32_16x16x32_bf16(kf[jf*2+kc],qf[0][kc],sacc[0][jf],0,0,0);
        sacc[1][jf]=__builtin_amdgcn_mfma_f32_16x16x32_bf16(kf[jf*2+kc],qf[1][kc],sacc[1][jf],0,0,0);
      }
    // ---- V fragment reads issued BEFORE softmax (latency hides under VALU) ----
    s16x8 vf[8];
    #pragma unroll
    for(int cf=0;cf<4;cf++)
      #pragma unroll
      for(int kc=0;kc<2;kc++)
        vf[cf*2+kc] = *(const s16x8*)&vt[cur][cf*16+l16][kc*32+lq*8];
    // ---- online softmax (base-2), lane-local defer-max, per subtile ----
    s16x8 pf[2][2];
    #pragma unroll
    for(int sub=0;sub<2;sub++){
      float mloc=-1e30f;
      #pragma unroll
      for(int jf=0;jf<4;jf++)
        #pragma unroll
        for(int r=0;r<4;r++) mloc=fmaxf(mloc,sacc[sub][jf][r]);
      if (!__all(mloc - mrun[sub] <= 8.0f)){
        mloc=fmaxf(mloc,__shfl_xor(mloc,16,64));
        mloc=fmaxf(mloc,__shfl_xor(mloc,32,64));
        const float mnew=fmaxf(mrun[sub],mloc);
        const float alpha=exp2a(mrun[sub]-mnew);
        #pragma unroll
        for(int cf=0;cf<4;cf++) oacc[sub][cf]*=alpha;
        lsum[sub]*=alpha;
        mrun[sub]=mnew;
      }
      float rs=0.f;
      float p[4][4];
      #pragma unroll
      for(int jf=0;jf<4;jf++)
        #pragma unroll
        for(int r=0;r<4;r++){
          float e=exp2a(sacc[sub][jf][r]-mrun[sub]);
          p[jf][r]=e; rs+=e;
        }
      lsum[sub]+=rs;                       // per-lane partial; reduced in epilogue
      #pragma unroll
      for(int kc=0;kc<2;kc++){
        union{s16x8 v; u32 u[4];} tt;
        tt.u[0]=pkbf(p[2*kc][0],  p[2*kc][1]);
        tt.u[1]=pkbf(p[2*kc][2],  p[2*kc][3]);
        tt.u[2]=pkbf(p[2*kc+1][0],p[2*kc+1][1]);
        tt.u[3]=pkbf(p[2*kc+1][2],p[2*kc+1][3]);
        pf[sub][kc]=tt.v;
      }
    }
    // ---- O^T += mfma(V^T, P^T), vf shared across subtiles ----
    #pragma unroll
    for(int cf=0;cf<4;cf++)
      #pragma unroll
      for(int kc=0;kc<2;kc++){
        oacc[0][cf]=__builtin_amdgcn_mfma_f32_16x16x32_bf16(vf[cf*2+kc],pf[0][kc],oacc[0][cf],0,0,0);
        oacc[1][cf]=__builtin_amdgcn_mfma_f32_16x16x32_bf16(vf[cf*2+kc],pf[1][kc],oacc[1][cf],0,0,0);
      }
    if (t<31){
      const int nb = cur^1;
      *(uint4*)&kt[nb][srow][sc]   = kr0;  *(uint4*)&kt[nb][srow][sc+8] = kr1;
      *(uint4*)&vt[nb][srow][sc]   = vr0;  *(uint4*)&vt[nb][srow][sc+8] = vr1;
    }
    __syncthreads();
  }
  // ---- epilogue: reduce lsum across the 4 lanes of each column, packed stores ----
  #pragma unroll
  for(int sub=0;sub<2;sub++){
    float l = lsum[sub];
    l += __shfl_xor(l,16,64);
    l += __shfl_xor(l,32,64);
    const float rinv = 1.f/l;
    const int n = n0 + w*32 + sub*16 + l16;
    #pragma unroll
    for(int cf=0;cf<4;cf++){
      uint2 st;
      st.x = pkbf(oacc[sub][cf][0]*rinv, oacc[sub][cf][1]*rinv);
      st.y = pkbf(oacc[sub][cf][2]*rinv, oacc[sub][cf][3]*rinv);
      *(uint2*)(catp + (size_t)n*512 + cf*16 + lq*4) = st;
    }
  }
}

// ---------------- Kernel 3: output projection + BN + LeakyReLU (fp32 out) ----------------
__global__ __launch_bounds__(256) void proj_kernel(
    const u16* __restrict__ cat, const u16* __restrict__ Wp,
    const float* __restrict__ gamma, const float* __restrict__ beta,
    const float* __restrict__ mean,  const float* __restrict__ var,
    float* __restrict__ out)
{
  const int m0 = blockIdx.x*64, j0 = blockIdx.y*64;
  __shared__ u16 at[64][40];
  __shared__ u16 bt[64][40];
  const int tid=threadIdx.x, lane=tid&63, w=tid>>6;
  const int wm=w>>1, wn=w&1, l16=lane&15, lq=lane>>4;
  f32x4 acc[2][2]={};
  const int srow=tid>>2, scol=(tid&3)*8;
  for(int c0=0;c0<512;c0+=32){
    *(uint4*)&at[srow][scol] = *(const uint4*)&cat[(size_t)(m0+srow)*512 + c0+scol];
    *(uint4*)&bt[srow][scol] = *(const uint4*)&Wp[(size_t)(j0+srow)*512 + c0+scol];
    __syncthreads();
    s16x8 af[2],bfr[2];
    #pragma unroll
    for(int mf=0;mf<2;mf++) af[mf]=ld_frag(&at[wm*32+mf*16+l16][lq*4]);
    #pragma unroll
    for(int nf=0;nf<2;nf++) bfr[nf]=ld_frag(&bt[wn*32+nf*16+l16][lq*4]);
    #pragma unroll
    for(int mf=0;mf<2;mf++)
      #pragma unroll
      for(int nf=0;nf<2;nf++)
        acc[mf][nf]=__builtin_amdgcn_mfma_f32_16x16x32_bf16(af[mf],bfr[nf],acc[mf][nf],0,0,0);
    __syncthreads();
  }
  #pragma unroll
  for(int nf=0;nf<2;nf++){
    const int co = j0 + wn*32 + nf*16 + l16;
    const float g=gamma[co], be=beta[co], mu=mean[co], va=var[co];
    const float a  = g * rsqrtf(va + 1e-5f);
    const float b2 = be - mu*a;
    #pragma unroll
    for(int mf=0;mf<2;mf++)
      #pragma unroll
      for(int r=0;r<4;r++){
        int m = m0 + wm*32 + mf*16 + lq*4 + r;
        float y = acc[mf][nf][r]*a + b2;
        y = (y>=0.f)? y : 0.01f*y;
        out[(size_t)m*256 + co] = y;
      }
  }
}

extern "C" void kernel_launch(void* const* d_in, const int* in_sizes, int n_in,
                              void* d_out, int out_size, void* d_ws, size_t ws_size,
                              hipStream_t stream)
{
  const float* x  = (const float*)d_in[0];
  const float* Wq = (const float*)d_in[1];
  const float* Wk = (const float*)d_in[2];
  const float* Wv = (const float*)d_in[3];
  const float* Wp = (const float*)d_in[4];
  const float* g  = (const float*)d_in[5];
  const float* be = (const float*)d_in[6];
  const float* mu = (const float*)d_in[7];
  const float* va = (const float*)d_in[8];

  u16* ws   = (u16*)d_ws;
  u16* x16  = ws;                         // 4,194,304 elems
  u16* wq16 = ws + 4194304;
  u16* wk16 = ws + 4325376;
  u16* wv16 = ws + 4456448;
  u16* wp16 = ws + 4587520;
  u16* kb   = ws + 4718592;

  cvt_kernel<<<4096, 256, 0, stream>>>(x,  x16,  1048576);
  cvt_kernel<<<128,  256, 0, stream>>>(Wq, wq16, 32768);
  cvt_kernel<<<128,  256, 0, stream>>>(Wk, wk16, 32768);
  cvt_kernel<<<128,  256, 0, stream>>>(Wv, wv16, 32768);
  cvt_kernel<<<128,  256, 0, stream>>>(Wp, wp16, 32768);

  // full path: kb(16MiB) + vb(16MiB) + cat(16MiB) after the 9.4MiB prefix
  const size_t full_elems = 4718592ull + 8388608ull*3ull;   // 29,884,416 u16
  if (ws_size >= full_elems*2ull){
    u16* vb  = kb + 8388608;
    u16* cat = vb + 8388608;
    kv_kernel<<<dim3(256,8,2), dim3(256), 0, stream>>>(x16, wk16, wv16, kb, vb);
    attn_kernel<<<dim3(1024), dim3(256), 0, stream>>>(x16, wq16, kb, vb, cat, 8);
    proj_kernel<<<dim3(256,4), dim3(256), 0, stream>>>(cat, wp16, g, be, mu, va, (float*)d_out);
  } else {
    u16* vb  = kb + 4194304;
    u16* cat = vb + 4194304;
    for (int half = 0; half < 2; ++half){
      const u16* xh = x16 + (size_t)half*2097152;
      u16* cath = cat + (size_t)half*4194304;
      kv_kernel<<<dim3(128,8,2), dim3(256), 0, stream>>>(xh, wk16, wv16, kb, vb);
      attn_kernel<<<dim3(512), dim3(256), 0, stream>>>(xh, wq16, kb, vb, cath, 4);
    }
    proj_kernel<<<dim3(256,4), dim3(256), 0, stream>>>(cat, wp16, g, be, mu, va, (float*)d_out);
  }
}

// Round 8
// 177.419 us; speedup vs baseline: 1.9645x; 1.0467x over previous
//
#include <hip/hip_runtime.h>
#include <hip/hip_bf16.h>

typedef unsigned short u16;
typedef unsigned int u32;
typedef float  f32x4 __attribute__((ext_vector_type(4)));
typedef short  s16x8 __attribute__((ext_vector_type(8)));

#define DEV static __device__ __forceinline__

DEV u16 f2bf(float f){ union{float f; unsigned int i;} c; c.f=f; unsigned int i=c.i;
                       return (u16)((i + 0x7FFFu + ((i>>16)&1u))>>16); }

// packed 2x f32 -> bf16x2 (v_cvt_pk_bf16_f32), low word = a
DEV u32 pkbf(float a, float b){
  union{ __hip_bfloat162 h; u32 u; } c;
  c.h = __float22bfloat162_rn(make_float2(a, b));
  return c.u;
}

DEV float exp2a(float x){
#if __has_builtin(__builtin_amdgcn_exp2f)
  return __builtin_amdgcn_exp2f(x);
#else
  return exp2f(x);
#endif
}

// 16x16x32 A/B fragment, plain layout: 4 contiguous bf16 at p, 4 at p+16.
// Same k-map mu(lq,e) for all operands (incl. D->B repacks) -> permutation-safe.
DEV s16x8 ld_frag(const u16* p){
  union{ s16x8 v; uint2 u[2]; } r;
  r.u[0] = *(const uint2*)(p);
  r.u[1] = *(const uint2*)(p+16);
  return r.v;
}

// ---------------- Kernel 0: fp32 -> bf16 ----------------
__global__ __launch_bounds__(256) void cvt_kernel(const float* __restrict__ src,
                                                  u16* __restrict__ dst, int n4)
{
  int i = blockIdx.x*256 + threadIdx.x;
  if (i >= n4) return;
  float4 v = *(const float4*)(src + (size_t)i*4);
  ushort4 o;
  o.x = f2bf(v.x); o.y = f2bf(v.y); o.z = f2bf(v.z); o.w = f2bf(v.w);
  *(ushort4*)(dst + (size_t)i*4) = o;
}

// ---------------- Kernel 1: K/V projection ----------------
// K stored [bh][n][kk'] (kk' fragment-permuted); V stored transposed
// [bh][dv][n'] (n' fragment-permuted within each 64-tile).
__global__ __launch_bounds__(256) void kv_kernel(
    const u16* __restrict__ x, const u16* __restrict__ Wk,
    const u16* __restrict__ Wv, u16* __restrict__ kbuf, u16* __restrict__ vbuf)
{
  const int isV = blockIdx.z;
  const u16* W = isV ? Wv : Wk;
  const int m0 = blockIdx.x*64, j0 = blockIdx.y*64;
  __shared__ u16 at[64][40];
  __shared__ u16 bt[64][40];
  const int tid = threadIdx.x, lane = tid&63, w = tid>>6;
  const int wm = w>>1, wn = w&1;
  const int l16 = lane&15, lq = lane>>4;
  f32x4 acc[2][2] = {};
  const int srow = tid>>2, scol = (tid&3)*8;
  for (int c0=0;c0<256;c0+=32){
    *(uint4*)&at[srow][scol] = *(const uint4*)&x[(size_t)(m0+srow)*256 + c0 + scol];
    *(uint4*)&bt[srow][scol] = *(const uint4*)&W[(size_t)(j0+srow)*256 + c0 + scol];
    __syncthreads();
    s16x8 af[2], bfr[2];
    #pragma unroll
    for(int mf=0;mf<2;mf++) af[mf]  = ld_frag(&at[wm*32+mf*16+l16][lq*4]);
    #pragma unroll
    for(int nf=0;nf<2;nf++) bfr[nf] = ld_frag(&bt[wn*32+nf*16+l16][lq*4]);
    #pragma unroll
    for(int mf=0;mf<2;mf++)
      #pragma unroll
      for(int nf=0;nf<2;nf++)
        acc[mf][nf] = __builtin_amdgcn_mfma_f32_16x16x32_bf16(af[mf], bfr[nf], acc[mf][nf],0,0,0);
    __syncthreads();
  }
  // D layout: col = l16, row = lq*4 + r
  if (!isV){
    #pragma unroll
    for(int mf=0;mf<2;mf++)
      #pragma unroll
      for(int nf=0;nf<2;nf++){
        const int j  = j0 + wn*32 + nf*16 + l16;
        const int hh = j>>6;
        const int kkp = wn*32 + (l16>>2)*8 + nf*4 + (l16&3);   // permuted kk
        #pragma unroll
        for(int r=0;r<4;r++){
          int m = m0 + wm*32 + mf*16 + lq*4 + r;
          int blx = m>>11, n = m&2047;
          kbuf[(size_t)((blx<<3)|hh)*131072 + (size_t)n*64 + kkp] = f2bf(acc[mf][nf][r]);
        }
      }
  } else {
    const int blx = m0>>11;
    #pragma unroll
    for(int mf=0;mf<2;mf++){
      const int nn = (m0&2047) + wm*32 + lq*8 + mf*4;          // permuted n-within-tile
      #pragma unroll
      for(int nf=0;nf<2;nf++){
        const int j  = j0 + wn*32 + nf*16 + l16;
        const int hh = j>>6, kk = j&63;
        uint2 st;
        st.x = pkbf(acc[mf][nf][0], acc[mf][nf][1]);
        st.y = pkbf(acc[mf][nf][2], acc[mf][nf][3]);
        *(uint2*)&vbuf[(size_t)((blx<<3)|hh)*131072 + (size_t)kk*2048 + nn] = st;
      }
    }
  }
}

// ---------------- Kernel 2: fused Q-projection + flash attention ----------------
// 128 q-rows per block; XCD-swizzled grid; scale folded into Q; NO-max softmax
// (P = exp2(S) raw; O/l scale-invariant); l accumulated via ones-MFMA;
// single-buffered LDS (18.4 KB) with stage-early + 2-deep global prefetch.
__global__ __launch_bounds__(256) void attn_kernel(
    const u16* __restrict__ x, const u16* __restrict__ Wq,
    const u16* __restrict__ kb, const u16* __restrict__ vb,
    u16* __restrict__ cat, int bh_per_xcd)
{
  const int lin = blockIdx.x;
  const int xcd = lin & 7, slot = lin >> 3;
  const int bhl = xcd*bh_per_xcd + (slot>>4);     // 16 q-tiles per bh
  const int n0  = (slot & 15) * 128;
  const int bl = bhl>>3, h = bhl&7;
  const u16* xg = x + (size_t)bl*524288;
  const u16* kg = kb + (size_t)bhl*131072;
  const u16* vg = vb + (size_t)bhl*131072;     // [dv][n'] layout
  u16* catp = cat + (size_t)bl*1048576 + h*64;
  const int tid=threadIdx.x, lane=tid&63, w=tid>>6;
  const int l16=lane&15, lq=lane>>4;

  __shared__ __align__(16) u16 kt[64][72];
  __shared__ __align__(16) u16 vt[64][72];

  // ---- Q on the fly for 2 subtiles; scale (0.125*log2e) folded into qf ----
  s16x8 qf[2][2];
  {
    const u16* wqh = Wq + (size_t)h*16384;
    s16x8 xf[2][8];
    #pragma unroll
    for(int sub=0;sub<2;sub++){
      const int row = n0 + w*32 + sub*16 + l16;
      #pragma unroll
      for(int kc8=0;kc8<8;kc8++) xf[sub][kc8] = ld_frag(xg + (size_t)row*256 + kc8*32 + lq*4);
    }
    f32x4 dq[2][4] = {};
    #pragma unroll
    for(int df=0;df<4;df++)
      #pragma unroll
      for(int kc8=0;kc8<8;kc8++){
        s16x8 wf = ld_frag(wqh + (size_t)(df*16+l16)*256 + kc8*32 + lq*4);
        dq[0][df] = __builtin_amdgcn_mfma_f32_16x16x32_bf16(wf, xf[0][kc8], dq[0][df],0,0,0);
        dq[1][df] = __builtin_amdgcn_mfma_f32_16x16x32_bf16(wf, xf[1][kc8], dq[1][df],0,0,0);
      }
    const float SCL = 0.125f * 1.44269504088896f;
    #pragma unroll
    for(int sub=0;sub<2;sub++)
      #pragma unroll
      for(int kc=0;kc<2;kc++){
        union{s16x8 v; u32 u[4];} t;
        t.u[0]=pkbf(dq[sub][2*kc][0]*SCL,  dq[sub][2*kc][1]*SCL);
        t.u[1]=pkbf(dq[sub][2*kc][2]*SCL,  dq[sub][2*kc][3]*SCL);
        t.u[2]=pkbf(dq[sub][2*kc+1][0]*SCL,dq[sub][2*kc+1][1]*SCL);
        t.u[3]=pkbf(dq[sub][2*kc+1][2]*SCL,dq[sub][2*kc+1][3]*SCL);
        qf[sub][kc]=t.v;
      }
  }

  // ---- ones A-fragment for l accumulation (permutation-immune) ----
  s16x8 ones;
  #pragma unroll
  for(int e=0;e<8;e++) ones[e] = (short)0x3F80;

  // ---- staging (straight row copies; layouts pre-permuted) ----
  const int srow = tid>>2, sc = (tid&3)*16;
  const u16* kst = kg + (size_t)srow*64 + sc;
  const u16* vst = vg + (size_t)srow*2048 + sc;
  uint4 kr0,kr1,vr0,vr1;
  // stage tile 0
  kr0 = *(const uint4*)(kst);   kr1 = *(const uint4*)(kst+8);
  vr0 = *(const uint4*)(vst);   vr1 = *(const uint4*)(vst+8);
  *(uint4*)&kt[srow][sc] = kr0;  *(uint4*)&kt[srow][sc+8] = kr1;
  *(uint4*)&vt[srow][sc] = vr0;  *(uint4*)&vt[srow][sc+8] = vr1;
  // prefetch tile 1 into regs
  kr0 = *(const uint4*)(kst + 4096);  kr1 = *(const uint4*)(kst + 4096 + 8);
  vr0 = *(const uint4*)(vst + 64);    vr1 = *(const uint4*)(vst + 64 + 8);
  __syncthreads();

  f32x4 oacc[2][4] = {};
  f32x4 accl[2] = {};

  for(int t=0;t<32;t++){
    // ---- fragment reads of tile t ----
    s16x8 kf[8], vf[8];
    #pragma unroll
    for(int jf=0;jf<4;jf++)
      #pragma unroll
      for(int kc=0;kc<2;kc++)
        kf[jf*2+kc] = *(const s16x8*)&kt[jf*16+l16][kc*32+lq*8];
    #pragma unroll
    for(int cf=0;cf<4;cf++)
      #pragma unroll
      for(int kc=0;kc<2;kc++)
        vf[cf*2+kc] = *(const s16x8*)&vt[cf*16+l16][kc*32+lq*8];

    if (t<31){
      __syncthreads();                       // all waves done reading tile t
      *(uint4*)&kt[srow][sc]   = kr0;  *(uint4*)&kt[srow][sc+8] = kr1;
      *(uint4*)&vt[srow][sc]   = vr0;  *(uint4*)&vt[srow][sc+8] = vr1;
      if (t<30){                             // 2-deep prefetch
        kr0 = *(const uint4*)(kst + (size_t)(t+2)*4096);
        kr1 = *(const uint4*)(kst + (size_t)(t+2)*4096 + 8);
        vr0 = *(const uint4*)(vst + (size_t)(t+2)*64);
        vr1 = *(const uint4*)(vst + (size_t)(t+2)*64 + 8);
      }
    }

    // ---- S^T = mfma(K, Q), kf shared across subtiles ----
    f32x4 sacc[2][4] = {};
    #pragma unroll
    for(int jf=0;jf<4;jf++)
      #pragma unroll
      for(int kc=0;kc<2;kc++){
        sacc[0][jf]=__builtin_amdgcn_mfma_f32_16x16x32_bf16(kf[jf*2+kc],qf[0][kc],sacc[0][jf],0,0,0);
        sacc[1][jf]=__builtin_amdgcn_mfma_f32_16x16x32_bf16(kf[jf*2+kc],qf[1][kc],sacc[1][jf],0,0,0);
      }
    // ---- softmax-lite: P = exp2(S) raw, pack to bf16 ----
    s16x8 pf[2][2];
    #pragma unroll
    for(int sub=0;sub<2;sub++)
      #pragma unroll
      for(int kc=0;kc<2;kc++){
        union{s16x8 v; u32 u[4];} tt;
        tt.u[0]=pkbf(exp2a(sacc[sub][2*kc][0]),  exp2a(sacc[sub][2*kc][1]));
        tt.u[1]=pkbf(exp2a(sacc[sub][2*kc][2]),  exp2a(sacc[sub][2*kc][3]));
        tt.u[2]=pkbf(exp2a(sacc[sub][2*kc+1][0]),exp2a(sacc[sub][2*kc+1][1]));
        tt.u[3]=pkbf(exp2a(sacc[sub][2*kc+1][2]),exp2a(sacc[sub][2*kc+1][3]));
        pf[sub][kc]=tt.v;
      }
    // ---- l += ones * P  (row-sums of P, per-lane column) ----
    #pragma unroll
    for(int kc=0;kc<2;kc++){
      accl[0]=__builtin_amdgcn_mfma_f32_16x16x32_bf16(ones,pf[0][kc],accl[0],0,0,0);
      accl[1]=__builtin_amdgcn_mfma_f32_16x16x32_bf16(ones,pf[1][kc],accl[1],0,0,0);
    }
    // ---- O^T += mfma(V^T, P^T), vf shared across subtiles ----
    #pragma unroll
    for(int cf=0;cf<4;cf++)
      #pragma unroll
      for(int kc=0;kc<2;kc++){
        oacc[0][cf]=__builtin_amdgcn_mfma_f32_16x16x32_bf16(vf[cf*2+kc],pf[0][kc],oacc[0][cf],0,0,0);
        oacc[1][cf]=__builtin_amdgcn_mfma_f32_16x16x32_bf16(vf[cf*2+kc],pf[1][kc],oacc[1][cf],0,0,0);
      }
    if (t<31) __syncthreads();               // writes of tile t+1 visible
  }
  // ---- epilogue: rinv from accl (all rows identical), packed stores ----
  #pragma unroll
  for(int sub=0;sub<2;sub++){
    const float rinv = 1.f/accl[sub][0];
    const int n = n0 + w*32 + sub*16 + l16;
    #pragma unroll
    for(int cf=0;cf<4;cf++){
      uint2 st;
      st.x = pkbf(oacc[sub][cf][0]*rinv, oacc[sub][cf][1]*rinv);
      st.y = pkbf(oacc[sub][cf][2]*rinv, oacc[sub][cf][3]*rinv);
      *(uint2*)(catp + (size_t)n*512 + cf*16 + lq*4) = st;
    }
  }
}

// ---------------- Kernel 3: output projection + BN + LeakyReLU (fp32 out) ----------------
__global__ __launch_bounds__(256) void proj_kernel(
    const u16* __restrict__ cat, const u16* __restrict__ Wp,
    const float* __restrict__ gamma, const float* __restrict__ beta,
    const float* __restrict__ mean,  const float* __restrict__ var,
    float* __restrict__ out)
{
  const int m0 = blockIdx.x*64, j0 = blockIdx.y*64;
  __shared__ u16 at[64][40];
  __shared__ u16 bt[64][40];
  const int tid=threadIdx.x, lane=tid&63, w=tid>>6;
  const int wm=w>>1, wn=w&1, l16=lane&15, lq=lane>>4;
  f32x4 acc[2][2]={};
  const int srow=tid>>2, scol=(tid&3)*8;
  for(int c0=0;c0<512;c0+=32){
    *(uint4*)&at[srow][scol] = *(const uint4*)&cat[(size_t)(m0+srow)*512 + c0+scol];
    *(uint4*)&bt[srow][scol] = *(const uint4*)&Wp[(size_t)(j0+srow)*512 + c0+scol];
    __syncthreads();
    s16x8 af[2],bfr[2];
    #pragma unroll
    for(int mf=0;mf<2;mf++) af[mf]=ld_frag(&at[wm*32+mf*16+l16][lq*4]);
    #pragma unroll
    for(int nf=0;nf<2;nf++) bfr[nf]=ld_frag(&bt[wn*32+nf*16+l16][lq*4]);
    #pragma unroll
    for(int mf=0;mf<2;mf++)
      #pragma unroll
      for(int nf=0;nf<2;nf++)
        acc[mf][nf]=__builtin_amdgcn_mfma_f32_16x16x32_bf16(af[mf],bfr[nf],acc[mf][nf],0,0,0);
    __syncthreads();
  }
  #pragma unroll
  for(int nf=0;nf<2;nf++){
    const int co = j0 + wn*32 + nf*16 + l16;
    const float g=gamma[co], be=beta[co], mu=mean[co], va=var[co];
    const float a  = g * rsqrtf(va + 1e-5f);
    const float b2 = be - mu*a;
    #pragma unroll
    for(int mf=0;mf<2;mf++)
      #pragma unroll
      for(int r=0;r<4;r++){
        int m = m0 + wm*32 + mf*16 + lq*4 + r;
        float y = acc[mf][nf][r]*a + b2;
        y = (y>=0.f)? y : 0.01f*y;
        out[(size_t)m*256 + co] = y;
      }
  }
}

extern "C" void kernel_launch(void* const* d_in, const int* in_sizes, int n_in,
                              void* d_out, int out_size, void* d_ws, size_t ws_size,
                              hipStream_t stream)
{
  const float* x  = (const float*)d_in[0];
  const float* Wq = (const float*)d_in[1];
  const float* Wk = (const float*)d_in[2];
  const float* Wv = (const float*)d_in[3];
  const float* Wp = (const float*)d_in[4];
  const float* g  = (const float*)d_in[5];
  const float* be = (const float*)d_in[6];
  const float* mu = (const float*)d_in[7];
  const float* va = (const float*)d_in[8];

  u16* ws   = (u16*)d_ws;
  u16* x16  = ws;                         // 4,194,304 elems
  u16* wq16 = ws + 4194304;
  u16* wk16 = ws + 4325376;
  u16* wv16 = ws + 4456448;
  u16* wp16 = ws + 4587520;
  u16* kb   = ws + 4718592;

  cvt_kernel<<<4096, 256, 0, stream>>>(x,  x16,  1048576);
  cvt_kernel<<<128,  256, 0, stream>>>(Wq, wq16, 32768);
  cvt_kernel<<<128,  256, 0, stream>>>(Wk, wk16, 32768);
  cvt_kernel<<<128,  256, 0, stream>>>(Wv, wv16, 32768);
  cvt_kernel<<<128,  256, 0, stream>>>(Wp, wp16, 32768);

  // full path: kb(16MiB) + vb(16MiB) + cat(16MiB) after the 9.4MiB prefix
  const size_t full_elems = 4718592ull + 8388608ull*3ull;   // 29,884,416 u16
  if (ws_size >= full_elems*2ull){
    u16* vb  = kb + 8388608;
    u16* cat = vb + 8388608;
    kv_kernel<<<dim3(256,8,2), dim3(256), 0, stream>>>(x16, wk16, wv16, kb, vb);
    attn_kernel<<<dim3(1024), dim3(256), 0, stream>>>(x16, wq16, kb, vb, cat, 8);
    proj_kernel<<<dim3(256,4), dim3(256), 0, stream>>>(cat, wp16, g, be, mu, va, (float*)d_out);
  } else {
    u16* vb  = kb + 4194304;
    u16* cat = vb + 4194304;
    for (int half = 0; half < 2; ++half){
      const u16* xh = x16 + (size_t)half*2097152;
      u16* cath = cat + (size_t)half*4194304;
      kv_kernel<<<dim3(128,8,2), dim3(256), 0, stream>>>(xh, wk16, wv16, kb, vb);
      attn_kernel<<<dim3(512), dim3(256), 0, stream>>>(xh, wq16, kb, vb, cath, 4);
    }
    proj_kernel<<<dim3(256,4), dim3(256), 0, stream>>>(cat, wp16, g, be, mu, va, (float*)d_out);
  }
}